// Round 31
// baseline (190.358 us; speedup 1.0000x reference)
//
#include <hip/hip_runtime.h>
#include <math.h>

// Problem constants (from reference)
#define BB   8      // batch
#define MM   4      // MAXM
#define DD   128    // DIM
#define NHH  8      // heads
#define QDD  16     // head dim
#define NN   256    // H*W
#define KO   128    // NH*QD
#define DTILE 8     // D-rows per out_kernel block

typedef float v2f __attribute__((ext_vector_type(2)));
#define PKFMA(a, b, c) __builtin_elementwise_fma((a), (b), (c))

typedef __attribute__((ext_vector_type(8))) short bf16x8;   // 8 bf16 (4 VGPR)
typedef __attribute__((ext_vector_type(4))) float f32x4;    // MFMA acc

__device__ inline unsigned short f2bf(float f) {            // RNE float->bf16
    union { float f; unsigned u; } v; v.f = f;
    unsigned r = v.u + 0x7FFF + ((v.u >> 16) & 1);
    return (unsigned short)(r >> 16);
}
__device__ inline float bf2f(unsigned short h) {
    union { unsigned u; float f; } v; v.u = ((unsigned)h) << 16;
    return v.f;
}
// split x = hi + lo (both bf16)
__device__ inline void bfsplit(float x, unsigned short& hi, unsigned short& lo) {
    hi = f2bf(x);
    lo = f2bf(x - bf2f(hi));
}
// e_mfma: (br | -bi<<16) -> (bi | br<<16)
__device__ inline bf16x8 derive_im(bf16x8 v) {
    union { bf16x8 v; unsigned u[4]; } in, out;
    in.v = v;
#pragma unroll
    for (int w = 0; w < 4; ++w)
        out.u[w] = ((in.u[w] >> 16) ^ 0x8000u) | (in.u[w] << 16);
    return out.v;
}
// a_mfma: (kx | ky<<16) -> (ky | (-kx)<<16)
__device__ inline bf16x8 derive_im2(bf16x8 v) {
    union { bf16x8 v; unsigned u[4]; } in, out;
    in.v = v;
#pragma unroll
    for (int w = 0; w < 4; ++w)
        out.u[w] = (in.u[w] >> 16) | ((in.u[w] ^ 0x8000u) << 16);
    return out.v;
}

// ---------------------------------------------------------------------------
// Kernel 0 (trig-free): pe[m,i,j] = exp(i*m*theta) = ((dx+i*dy)/r)^m.
// ---------------------------------------------------------------------------
__global__ void pe_kernel(float2* __restrict__ peIJ, float2* __restrict__ peT) {
    int bid = blockIdx.x;           // m*N + i
    int m = bid >> 8;
    int i = bid & 255;
    int j = threadIdx.x;
    float dy = (float)((j >> 4) - (i >> 4));
    float dx = (float)((j & 15) - (i & 15));
    float r2 = dx * dx + dy * dy;
    float c1 = 1.f, s1 = 0.f;
    if (r2 > 0.f) {
        float rinv = rsqrtf(r2);
        c1 = dx * rinv; s1 = dy * rinv;
    }
    float c = 1.f, s = 0.f;
    for (int k = 0; k < m; ++k) {   // m is block-uniform (0..3)
        float nc = c * c1 - s * s1;
        s = c * s1 + s * c1;
        c = nc;
    }
    peIJ[(m * NN + i) * NN + j] = make_float2(c, s);
    peT[(m * NN + j) * NN + i] = make_float2(c, s);
}

// ---------------------------------------------------------------------------
// Kernel 1a: convA — emb -> A' split-bf16 (k = 2D|2D+1 = ar|ai).
// ---------------------------------------------------------------------------
__global__ void convA_kernel(const float* __restrict__ er, const float* __restrict__ ei,
                             unsigned int* __restrict__ AbfHi, unsigned int* __restrict__ AbfLo) {
    int tmh = blockIdx.x;                 // 0..95
    int base = tmh * QDD * DD;
#pragma unroll
    for (int it = 0; it < 8; ++it) {
        int idx = threadIdx.x + it * 256;  // q*128+D
        float ar = er[base + idx];
        float ai = ei[base + idx];
        unsigned short arh, arl, aih, ail;
        bfsplit(ar, arh, arl);
        bfsplit(ai, aih, ail);
        AbfHi[base + idx] = (unsigned int)arh | ((unsigned int)aih << 16);
        AbfLo[base + idx] = (unsigned int)arl | ((unsigned int)ail << 16);
    }
}

// ---------------------------------------------------------------------------
// Kernel 1b: convB — x -> split-bf16 Bre (Bim derived in-register in e_mfma).
// ---------------------------------------------------------------------------
__global__ void convB_kernel(const float* __restrict__ xr, const float* __restrict__ xi,
                             unsigned int* __restrict__ BreHi, unsigned int* __restrict__ BreLo) {
    int bid = blockIdx.x;                 // 256 = 32 bm x 8 Dg
    int bm = bid >> 3;
    int Dg = bid & 7;
    int D0 = Dg * 16;
    int tid = threadIdx.x;

    __shared__ float sxr[16][257];
    __shared__ float sxi[16][257];

    const float* xrp = xr + (size_t)bm * DD * NN;
    const float* xip = xi + (size_t)bm * DD * NN;
#pragma unroll
    for (int it = 0; it < 16; ++it) {
        int i2 = tid + it * 256;
        int r = i2 >> 8, c = i2 & 255;
        sxr[r][c] = xrp[(size_t)(D0 + r) * NN + c];
        sxi[r][c] = xip[(size_t)(D0 + r) * NN + c];
    }
    __syncthreads();

    int n = tid;
    unsigned int reh[16], rel_[16];
#pragma unroll
    for (int d = 0; d < 16; ++d) {
        float br = sxr[d][n];
        float bi = sxi[d][n];
        unsigned short brh, brl, bih, bil;
        bfsplit(br, brh, brl);
        bfsplit(bi, bih, bil);
        reh[d]  = (unsigned int)brh | ((unsigned int)(bih ^ 0x8000) << 16);
        rel_[d] = (unsigned int)brl | ((unsigned int)(bil ^ 0x8000) << 16);
    }
    size_t ob = (size_t)bm * 32768 + (size_t)n * 128 + D0;
#pragma unroll
    for (int w = 0; w < 4; ++w) {
        ((uint4*)(BreHi + ob))[w] = make_uint4(reh[4*w], reh[4*w+1], reh[4*w+2], reh[4*w+3]);
        ((uint4*)(BreLo + ob))[w] = make_uint4(rel_[4*w], rel_[4*w+1], rel_[4*w+2], rel_[4*w+3]);
    }
}

// ---------------------------------------------------------------------------
// Kernel 1c (MFMA v2, t-merged): block = (pair, h) computes ALL 3 t planes.
// ---------------------------------------------------------------------------
__global__ __launch_bounds__(256, 1)
void e_mfma_kernel(const unsigned short* __restrict__ AbfHi,
                   const unsigned short* __restrict__ AbfLo,
                   const unsigned short* __restrict__ BreHi,
                   const unsigned short* __restrict__ BreLo,
                   float2* __restrict__ E) {
    int bid = blockIdx.x;                 // 256 = 8 xcd x 32 idx
    int xcd = bid & 7;
    int idx = bid >> 3;                   // 0..31
    int pair = xcd * 4 + (idx & 3);       // b*MM+m (XCD-pinned B panels)
    int h = idx >> 2;                     // 0..7
    int b = pair >> 2, m = pair & 3;
    int tid = threadIdx.x;
    int wav = tid >> 6, lane = tid & 63;
    int lo = lane & 15, hi = lane >> 4;

    const unsigned short* AH[3];
    const unsigned short* AL[3];
#pragma unroll
    for (int t = 0; t < 3; ++t) {
        size_t aoff = ((size_t)((t * MM + m) * NHH + h)) * QDD * 256;
        AH[t] = AbfHi + aoff;
        AL[t] = AbfLo + aoff;
    }
    size_t boff = (size_t)pair * 256 * 256;
    const unsigned short* BrH = BreHi + boff;
    const unsigned short* BrL = BreLo + boff;

    f32x4 accRe[3][4], accIm[3][4];
#pragma unroll
    for (int t = 0; t < 3; ++t)
#pragma unroll
        for (int nt = 0; nt < 4; ++nt) {
            accRe[t][nt] = (f32x4)(0.f);
            accIm[t][nt] = (f32x4)(0.f);
        }

#pragma unroll
    for (int ks = 0; ks < 8; ++ks) {
        int k0 = ks * 32;
        int arow = lo * 256 + k0 + hi * 8;
        bf16x8 aH[3], aL[3];
#pragma unroll
        for (int t = 0; t < 3; ++t) {
            aH[t] = *(const bf16x8*)(AH[t] + arow);
            aL[t] = *(const bf16x8*)(AL[t] + arow);
        }
#pragma unroll
        for (int nt = 0; nt < 4; ++nt) {
            int n0 = (wav * 4 + nt) * 16;
            size_t brow = (size_t)(n0 + lo) * 256 + k0 + hi * 8;
            bf16x8 brh = *(const bf16x8*)(BrH + brow);
            bf16x8 brl = *(const bf16x8*)(BrL + brow);
            bf16x8 bih = derive_im(brh);
            bf16x8 bil = derive_im(brl);
#pragma unroll
            for (int t = 0; t < 3; ++t) {
                accRe[t][nt] = __builtin_amdgcn_mfma_f32_16x16x32_bf16(aH[t], brh, accRe[t][nt], 0, 0, 0);
                accRe[t][nt] = __builtin_amdgcn_mfma_f32_16x16x32_bf16(aH[t], brl, accRe[t][nt], 0, 0, 0);
                accRe[t][nt] = __builtin_amdgcn_mfma_f32_16x16x32_bf16(aL[t], brh, accRe[t][nt], 0, 0, 0);
                accIm[t][nt] = __builtin_amdgcn_mfma_f32_16x16x32_bf16(aH[t], bih, accIm[t][nt], 0, 0, 0);
                accIm[t][nt] = __builtin_amdgcn_mfma_f32_16x16x32_bf16(aH[t], bil, accIm[t][nt], 0, 0, 0);
                accIm[t][nt] = __builtin_amdgcn_mfma_f32_16x16x32_bf16(aL[t], bih, accIm[t][nt], 0, 0, 0);
            }
        }
    }

#pragma unroll
    for (int t = 0; t < 3; ++t) {
        size_t ebase = (size_t)((((t * BB + b) * MM + m) * NHH + h) * QDD) * NN;
#pragma unroll
        for (int nt = 0; nt < 4; ++nt) {
            int n0 = (wav * 4 + nt) * 16;
#pragma unroll
            for (int reg = 0; reg < 4; ++reg) {
                int q = hi * 4 + reg;
                E[ebase + (size_t)q * NN + n0 + lo] = make_float2(accRe[t][nt][reg], accIm[t][nt][reg]);
            }
        }
    }
}

// ---------------------------------------------------------------------------
// Kernel 2: QE[b,m,h,i] = sum_q conj(E0[b,m,h,q,i]) * enc0[m,h,q]
// ---------------------------------------------------------------------------
__global__ void qe_kernel(const float2* __restrict__ E,
                          const float* __restrict__ encr, const float* __restrict__ enci,
                          float2* __restrict__ QE) {
    int bid = blockIdx.x;                 // (b*MM+m)*NHH + h
    int i = threadIdx.x;
    const float2* e0 = E + (size_t)(bid) * QDD * NN;   // t=0 plane
    int h = bid & 7;
    int bm = bid >> 3;
    int m = bm & 3;
    int encbase = (m * NHH + h) * QDD;    // enc[0,m,h,0,q,0]
    float ar = 0.f, ai = 0.f;
#pragma unroll
    for (int q = 0; q < QDD; ++q) {
        float2 e = e0[q * NN + i];
        float cr = encr[encbase + q], ci = enci[encbase + q];
        // conj(e) * enc
        ar = fmaf(e.x, cr, fmaf( e.y, ci, ar));
        ai = fmaf(e.x, ci, fmaf(-e.y, cr, ai));
    }
    QE[(size_t)bid * NN + i] = make_float2(ar, ai);
}

// ---------------------------------------------------------------------------
// Kernel 3a: conv_ak — E(t0),E(t1) -> split-bf16 k-fastest panels per bh.
// Ea/Kb uint idx = (bh*256 + n)*64 + (m*16+q); uint = (re | im<<16).
// ---------------------------------------------------------------------------
__global__ void conv_ak_kernel(const float2* __restrict__ E,
                               unsigned int* __restrict__ EaHi, unsigned int* __restrict__ EaLo,
                               unsigned int* __restrict__ KbHi, unsigned int* __restrict__ KbLo) {
    int bh = blockIdx.x;                  // 0..63
    int b = bh >> 3, h = bh & 7;
    int tid = threadIdx.x;
    int mq = tid & 63;                    // m*16+q
    int m = mq >> 4, q = mq & 15;
    int ng = tid >> 6;                    // n-quarter 0..3

    const float2* e0 = E + ((size_t)(((0 * BB + b) * MM + m) * NHH + h) * QDD + q) * NN;
    const float2* k1 = E + ((size_t)(((1 * BB + b) * MM + m) * NHH + h) * QDD + q) * NN;

    for (int nn = 0; nn < 64; ++nn) {
        int n = ng * 64 + nn;
        float2 e = e0[n];
        float2 k = k1[n];
        unsigned short exh, exl, eyh, eyl, kxh, kxl, kyh, kyl;
        bfsplit(e.x, exh, exl);
        bfsplit(e.y, eyh, eyl);
        bfsplit(k.x, kxh, kxl);
        bfsplit(k.y, kyh, kyl);
        size_t oi = ((size_t)bh * 256 + n) * 64 + mq;
        EaHi[oi] = (unsigned int)exh | ((unsigned int)eyh << 16);
        EaLo[oi] = (unsigned int)exl | ((unsigned int)eyl << 16);
        KbHi[oi] = (unsigned int)kxh | ((unsigned int)kyh << 16);
        KbLo[oi] = (unsigned int)kxl | ((unsigned int)kyl << 16);
    }
}

// ---------------------------------------------------------------------------
// Kernel 3b (a_mfma): Scores[bh][i][j] = sum_k Ea[i][k]*Kb_re/im[j][k]
// (K=128 real) + pe epilogue. Block = (bh, iquad); wave = i-tile.
// ---------------------------------------------------------------------------
__global__ __launch_bounds__(256, 1)
void a_mfma_kernel(const unsigned short* __restrict__ EaHi,
                   const unsigned short* __restrict__ EaLo,
                   const unsigned short* __restrict__ KbHi,
                   const unsigned short* __restrict__ KbLo,
                   const float2* __restrict__ QE,
                   const float2* __restrict__ peIJ,
                   float2* __restrict__ Scores) {
    int bid = blockIdx.x;                 // 256 = 8 xcd x 32 idx
    int xcd = bid & 7;
    int idx = bid >> 3;                   // 0..31
    int bh = xcd * 8 + (idx & 7);         // K-panel XCD-pinned
    int iquad = idx >> 3;                 // 0..3
    int b = bh >> 3, h = bh & 7;
    int tid = threadIdx.x;
    int wav = tid >> 6, lane = tid & 63;
    int lo = lane & 15, hi = lane >> 4;
    int it = iquad * 4 + wav;             // this wave's i-tile (0..15)

    const unsigned short* EaH = EaHi + (size_t)bh * 256 * 128;
    const unsigned short* EaL = EaLo + (size_t)bh * 256 * 128;
    const unsigned short* KbH = KbHi + (size_t)bh * 256 * 128;
    const unsigned short* KbL = KbLo + (size_t)bh * 256 * 128;

    f32x4 accRe[16], accIm[16];
#pragma unroll
    for (int nt = 0; nt < 16; ++nt) { accRe[nt] = (f32x4)(0.f); accIm[nt] = (f32x4)(0.f); }

#pragma unroll
    for (int ks = 0; ks < 4; ++ks) {
        int k0 = ks * 32;
        size_t arow = (size_t)(it * 16 + lo) * 128 + k0 + hi * 8;
        bf16x8 aH = *(const bf16x8*)(EaH + arow);
        bf16x8 aL = *(const bf16x8*)(EaL + arow);
#pragma unroll
        for (int nt = 0; nt < 16; ++nt) {
            size_t brow = (size_t)(nt * 16 + lo) * 128 + k0 + hi * 8;
            bf16x8 brh = *(const bf16x8*)(KbH + brow);
            bf16x8 brl = *(const bf16x8*)(KbL + brow);
            bf16x8 bih = derive_im2(brh);
            bf16x8 bil = derive_im2(brl);
            accRe[nt] = __builtin_amdgcn_mfma_f32_16x16x32_bf16(aH, brh, accRe[nt], 0, 0, 0);
            accRe[nt] = __builtin_amdgcn_mfma_f32_16x16x32_bf16(aH, brl, accRe[nt], 0, 0, 0);
            accRe[nt] = __builtin_amdgcn_mfma_f32_16x16x32_bf16(aL, brh, accRe[nt], 0, 0, 0);
            accIm[nt] = __builtin_amdgcn_mfma_f32_16x16x32_bf16(aH, bih, accIm[nt], 0, 0, 0);
            accIm[nt] = __builtin_amdgcn_mfma_f32_16x16x32_bf16(aH, bil, accIm[nt], 0, 0, 0);
            accIm[nt] = __builtin_amdgcn_mfma_f32_16x16x32_bf16(aL, bih, accIm[nt], 0, 0, 0);
        }
    }

    // epilogue: + sum_m QE[b,m,h,i]*pe[m,i,j]; write Scores.
    float2 qe[MM][4];
#pragma unroll
    for (int m = 0; m < MM; ++m)
#pragma unroll
        for (int reg = 0; reg < 4; ++reg) {
            int i = it * 16 + hi * 4 + reg;
            qe[m][reg] = QE[(size_t)((b * MM + m) * NHH + h) * NN + i];
        }

#pragma unroll
    for (int nt = 0; nt < 16; ++nt) {
#pragma unroll
        for (int reg = 0; reg < 4; ++reg) {
            int i = it * 16 + hi * 4 + reg;
            int j = nt * 16 + lo;
            float ar = accRe[nt][reg];
            float ai = accIm[nt][reg];
#pragma unroll
            for (int m = 0; m < MM; ++m) {
                float2 p = peIJ[(size_t)(m * NN + i) * NN + j];
                float2 e1 = qe[m][reg];
                ar = fmaf(e1.x, p.x, fmaf(-e1.y, p.y, ar));
                ai = fmaf(e1.x, p.y, fmaf( e1.y, p.x, ai));
            }
            Scores[(size_t)(bh * NN + i) * NN + j] = make_float2(ar, ai);
        }
    }
}

// ---------------------------------------------------------------------------
// Kernel 4: row softmax of |A|/4 over j; writes TRANSPOSED Aw:
//   AwT[(bh*N + j)*N + i]
// ---------------------------------------------------------------------------
__global__ void softmax_kernel(const float2* __restrict__ A, float* __restrict__ AwT) {
    int row = blockIdx.x;                 // (b*NHH+h)*NN + i
    int j = threadIdx.x;
    float2 a = A[(size_t)row * NN + j];
    float v = sqrtf(fmaf(a.x, a.x, a.y * a.y)) * 0.25f;

    __shared__ float smax[4];
    __shared__ float ssum[4];
    int lane = threadIdx.x & 63;
    int wid  = threadIdx.x >> 6;

    float mv = v;
#pragma unroll
    for (int off = 32; off > 0; off >>= 1) mv = fmaxf(mv, __shfl_xor(mv, off));
    if (lane == 0) smax[wid] = mv;
    __syncthreads();
    float mx = fmaxf(fmaxf(smax[0], smax[1]), fmaxf(smax[2], smax[3]));

    float e = expf(v - mx);
    float sv = e;
#pragma unroll
    for (int off = 32; off > 0; off >>= 1) sv += __shfl_xor(sv, off);
    if (lane == 0) ssum[wid] = sv;
    __syncthreads();
    float sum = ssum[0] + ssum[1] + ssum[2] + ssum[3];

    float aw = e / sum;
    int bh = row >> 8;
    int i  = row & 255;
    AwT[(size_t)(bh * NN + j) * NN + i] = aw;
}

// ---------------------------------------------------------------------------
// Kernel 5 (qh-split + XCD swizzle): 512 blocks = 64 idx x 8 xcd.
// ---------------------------------------------------------------------------
__global__ __launch_bounds__(512)
void res_kernel(const float2* __restrict__ E, const float* __restrict__ AwT,
                const float2* __restrict__ peT,
                const float* __restrict__ encr, const float* __restrict__ enci,
                float2* __restrict__ Res) {
    int bid = blockIdx.x;
    int xcd = bid & 7;
    int idx = bid >> 3;                   // 0..63
    int bh = xcd * 8 + (idx & 7);         // b*NHH+h
    int mqh = idx >> 3;                   // 0..7
    int m  = mqh >> 1;
    int qh = mqh & 1;
    int h = bh & 7;
    int b = bh >> 3;
    int i = threadIdx.x & 255;
    int g = threadIdx.x >> 8;             // j-half 0/1

    __shared__ float2 sv[8][NN];          // 16 KB: this qh's 8 V rows
    __shared__ float2 spA[NN][9];         // 18 KB: g=1 partials (8 acc + PA)
    __shared__ float2 senc[8];

    const float2* V = E + ((size_t)(((2 * BB + b) * MM + m) * NHH + h) * QDD + qh * 8) * NN;
    for (int i2 = threadIdx.x; i2 < 8 * NN; i2 += 512) sv[i2 >> 8][i2 & 255] = V[i2];
    if (threadIdx.x < 8) {
        int eb = ((MM + m) * NHH + h) * QDD + qh * 8 + threadIdx.x;   // enc[1,...]
        senc[threadIdx.x] = make_float2(encr[eb], enci[eb]);
    }
    __syncthreads();

    float accr[8], acci[8];
#pragma unroll
    for (int q = 0; q < 8; ++q) { accr[q] = 0.f; acci[q] = 0.f; }
    float par = 0.f, pai = 0.f;

    const float*  awp = AwT + (size_t)((b * NHH + h) * NN) * NN + i;
    const float2* pep = peT + (size_t)(m * NN) * NN + i;
    int j0 = g * (NN / 2);
    for (int j = j0; j < j0 + NN / 2; ++j) {
        float aw  = awp[(size_t)j * NN];      // coalesced over i
        float2 p  = pep[(size_t)j * NN];      // coalesced over i
        par = fmaf(p.x, aw, par);
        pai = fmaf(p.y, aw, pai);
#pragma unroll
        for (int q = 0; q < 8; ++q) {
            float2 vv = sv[q][j];             // wave-uniform -> broadcast
            accr[q] = fmaf(vv.x, aw, accr[q]);
            acci[q] = fmaf(vv.y, aw, acci[q]);
        }
    }

    if (g == 1) {
#pragma unroll
        for (int q = 0; q < 8; ++q) spA[i][q] = make_float2(accr[q], acci[q]);
        spA[i][8] = make_float2(par, pai);
    }
    __syncthreads();
    if (g == 0) {
#pragma unroll
        for (int q = 0; q < 8; ++q) {
            float2 o = spA[i][q];
            accr[q] += o.x; acci[q] += o.y;
        }
        float2 o = spA[i][8];
        par += o.x; pai += o.y;

        float2* rp = Res + ((size_t)((b * MM + m) * KO + h * QDD + qh * 8)) * NN + i;
#pragma unroll
        for (int q = 0; q < 8; ++q) {
            float2 e1 = senc[q];
            float rr = accr[q] + e1.x * par - e1.y * pai;
            float ri = acci[q] + e1.x * pai + e1.y * par;
            rp[(size_t)q * NN] = make_float2(rr, ri);
        }
    }
}

// ---------------------------------------------------------------------------
// Kernel 6 (DTILE=8 + XCD swizzle): out[b,m,D,n] = sum_k w_out*res.
// ---------------------------------------------------------------------------
__global__ void out_kernel(const float2* __restrict__ Res,
                           const float* __restrict__ wor, const float* __restrict__ woi,
                           float* __restrict__ out) {
    int bid = blockIdx.x;
    int xcd = bid & 7;
    int idx = bid >> 3;                   // 0..63
    int bm = xcd * 4 + (idx & 3);         // b*MM+m, 0..31
    int dt = idx >> 2;                    // 0..15
    int n = threadIdx.x;
    int D0 = dt * DTILE;
    int m = bm & 3;

    __shared__ float2 sw[DTILE][KO];      // 8 KB
    for (int i2 = threadIdx.x; i2 < DTILE * KO; i2 += 256) {
        int d = i2 >> 7, k = i2 & 127;
        int wb = (m * DD + D0 + d) * KO + k;
        sw[d][k] = make_float2(wor[wb], woi[wb]);
    }
    __syncthreads();

    const float2* rp = Res + (size_t)(bm * KO) * NN + n;
    float ar[DTILE], ai[DTILE];
#pragma unroll
    for (int d = 0; d < DTILE; ++d) { ar[d] = 0.f; ai[d] = 0.f; }

    for (int k = 0; k < KO; ++k) {
        float2 r = rp[(size_t)k * NN];    // coalesced
#pragma unroll
        for (int d = 0; d < DTILE; ++d) {
            float2 w = sw[d][k];          // broadcast
            ar[d] = fmaf(w.x, r.x, fmaf(-w.y, r.y, ar[d]));
            ai[d] = fmaf(w.x, r.y, fmaf( w.y, r.x, ai[d]));
        }
    }
#pragma unroll
    for (int d = 0; d < DTILE; ++d) {
        size_t ob = (size_t)(bm * DD + D0 + d) * NN + n;
        out[ob] = ar[d];
        out[(size_t)BB * MM * DD * NN + ob] = ai[d];
    }
}

// ---------------------------------------------------------------------------
extern "C" void kernel_launch(void* const* d_in, const int* in_sizes, int n_in,
                              void* d_out, int out_size, void* d_ws, size_t ws_size,
                              hipStream_t stream) {
    (void)in_sizes; (void)n_in; (void)out_size; (void)ws_size;

    const float* x_re   = (const float*)d_in[0];
    const float* x_im   = (const float*)d_in[1];
    const float* emb_re = (const float*)d_in[2];
    const float* emb_im = (const float*)d_in[3];
    const float* enc_re = (const float*)d_in[4];
    const float* enc_im = (const float*)d_in[5];
    const float* out_re = (const float*)d_in[6];
    const float* out_im = (const float*)d_in[7];
    float* out = (float*)d_out;

    // Workspace layout (floats). Total ~155.7 MB.
    float* ws = (float*)d_ws;
    size_t off = 0;
    float2* peIJ = (float2*)(ws + off); off += (size_t)MM * NN * NN * 2;          // 524288
    float2* peT  = (float2*)(ws + off); off += (size_t)MM * NN * NN * 2;          // 524288
    float2* E    = (float2*)(ws + off); off += (size_t)3 * BB * MM * NHH * QDD * NN * 2; // 25165824
    float2* QE   = (float2*)(ws + off); off += (size_t)BB * MM * NHH * NN * 2;    // 131072
    float2* A    = (float2*)(ws + off); off += (size_t)BB * NHH * NN * NN * 2;    // 8388608 fl
    float*  AwT  = (float*)(ws + off);  off += (size_t)BB * NHH * NN * NN;        // 4194304 fl

    // Region plan (ALIASING FIX vs r30: Scores needs the FULL 33.5MB A region;
    // Ea/Kb (16.78MB) live in the AwT region, dead until softmax writes AwT):
    //  1) convA/convB stage Abf/Bre in A region; e_mfma reads -> writes E.
    //  2) conv_ak reads E -> writes Ea/Kb into AwT region.
    //  3) a_mfma reads Ea/Kb -> writes Scores over FULL A region (staging dead).
    //  4) softmax reads Scores(A) -> writes AwT (Ea/Kb dead).
    //  5) res reads AwT + V(E t2) -> writes Res into A region start (Scores dead).
    unsigned int* AbfHi = (unsigned int*)A;
    unsigned int* AbfLo = AbfHi + (size_t)96 * QDD * DD;
    unsigned int* BreHi = AbfLo + (size_t)96 * QDD * DD;
    unsigned int* BreLo = BreHi + (size_t)32 * 256 * 128;

    unsigned int* EaHi = (unsigned int*)AwT;                      // 4 x 1048576 uints
    unsigned int* EaLo = EaHi + (size_t)64 * 256 * 64;            //  = 16.78MB exact
    unsigned int* KbHi = EaLo + (size_t)64 * 256 * 64;
    unsigned int* KbLo = KbHi + (size_t)64 * 256 * 64;

    float2* Scores = A;   // full 33.5MB A region
    float2* Res    = A;   // first 8.4MB of A region, after Scores is dead

    pe_kernel<<<MM * NN, 256, 0, stream>>>(peIJ, peT);
    convA_kernel<<<96, 256, 0, stream>>>(emb_re, emb_im, AbfHi, AbfLo);
    convB_kernel<<<256, 256, 0, stream>>>(x_re, x_im, BreHi, BreLo);
    e_mfma_kernel<<<256, 256, 0, stream>>>(
        (const unsigned short*)AbfHi, (const unsigned short*)AbfLo,
        (const unsigned short*)BreHi, (const unsigned short*)BreLo, E);
    conv_ak_kernel<<<64, 256, 0, stream>>>(E, EaHi, EaLo, KbHi, KbLo);
    qe_kernel<<<BB * MM * NHH, 256, 0, stream>>>(E, enc_re, enc_im, QE);
    a_mfma_kernel<<<256, 256, 0, stream>>>(
        (const unsigned short*)EaHi, (const unsigned short*)EaLo,
        (const unsigned short*)KbHi, (const unsigned short*)KbLo,
        QE, peIJ, Scores);
    softmax_kernel<<<BB * NHH * NN, 256, 0, stream>>>(Scores, AwT);
    res_kernel<<<BB * MM * NHH * 2, 512, 0, stream>>>(E, AwT, peT, enc_re, enc_im, Res);
    out_kernel<<<BB * MM * (DD / DTILE), 256, 0, stream>>>(Res, out_re, out_im, out);
}

// Round 32
// 163.979 us; speedup vs baseline: 1.1609x; 1.1609x over previous
//
#include <hip/hip_runtime.h>
#include <math.h>

// Problem constants (from reference)
#define BB   8      // batch
#define MM   4      // MAXM
#define DD   128    // DIM
#define NHH  8      // heads
#define QDD  16     // head dim
#define NN   256    // H*W
#define KO   128    // NH*QD
#define DTILE 8     // D-rows per out_kernel block

typedef float v2f __attribute__((ext_vector_type(2)));
#define PKFMA(a, b, c) __builtin_elementwise_fma((a), (b), (c))

typedef __attribute__((ext_vector_type(8))) short bf16x8;   // 8 bf16 (4 VGPR)
typedef __attribute__((ext_vector_type(4))) float f32x4;    // MFMA acc

__device__ inline unsigned short f2bf(float f) {            // RNE float->bf16
    union { float f; unsigned u; } v; v.f = f;
    unsigned r = v.u + 0x7FFF + ((v.u >> 16) & 1);
    return (unsigned short)(r >> 16);
}
__device__ inline float bf2f(unsigned short h) {
    union { unsigned u; float f; } v; v.u = ((unsigned)h) << 16;
    return v.f;
}
// split x = hi + lo (both bf16)
__device__ inline void bfsplit(float x, unsigned short& hi, unsigned short& lo) {
    hi = f2bf(x);
    lo = f2bf(x - bf2f(hi));
}
// e_mfma: (br | -bi<<16) -> (bi | br<<16)
__device__ inline bf16x8 derive_im(bf16x8 v) {
    union { bf16x8 v; unsigned u[4]; } in, out;
    in.v = v;
#pragma unroll
    for (int w = 0; w < 4; ++w)
        out.u[w] = ((in.u[w] >> 16) ^ 0x8000u) | (in.u[w] << 16);
    return out.v;
}
// a_mfma: (kx | ky<<16) -> (ky | (-kx)<<16)
__device__ inline bf16x8 derive_im2(bf16x8 v) {
    union { bf16x8 v; unsigned u[4]; } in, out;
    in.v = v;
#pragma unroll
    for (int w = 0; w < 4; ++w)
        out.u[w] = (in.u[w] >> 16) | ((in.u[w] ^ 0x8000u) << 16);
    return out.v;
}

// ---------------------------------------------------------------------------
// Kernel 0 (trig-free): pe[m,i,j] = exp(i*m*theta) = ((dx+i*dy)/r)^m.
// ---------------------------------------------------------------------------
__global__ void pe_kernel(float2* __restrict__ peIJ, float2* __restrict__ peT) {
    int bid = blockIdx.x;           // m*N + i
    int m = bid >> 8;
    int i = bid & 255;
    int j = threadIdx.x;
    float dy = (float)((j >> 4) - (i >> 4));
    float dx = (float)((j & 15) - (i & 15));
    float r2 = dx * dx + dy * dy;
    float c1 = 1.f, s1 = 0.f;
    if (r2 > 0.f) {
        float rinv = rsqrtf(r2);
        c1 = dx * rinv; s1 = dy * rinv;
    }
    float c = 1.f, s = 0.f;
    for (int k = 0; k < m; ++k) {   // m is block-uniform (0..3)
        float nc = c * c1 - s * s1;
        s = c * s1 + s * c1;
        c = nc;
    }
    peIJ[(m * NN + i) * NN + j] = make_float2(c, s);
    peT[(m * NN + j) * NN + i] = make_float2(c, s);
}

// ---------------------------------------------------------------------------
// Kernel 1a: convA — emb -> A' split-bf16 (k = 2D|2D+1 = ar|ai).
// ---------------------------------------------------------------------------
__global__ void convA_kernel(const float* __restrict__ er, const float* __restrict__ ei,
                             unsigned int* __restrict__ AbfHi, unsigned int* __restrict__ AbfLo) {
    int tmh = blockIdx.x;                 // 0..95
    int base = tmh * QDD * DD;
#pragma unroll
    for (int it = 0; it < 8; ++it) {
        int idx = threadIdx.x + it * 256;  // q*128+D
        float ar = er[base + idx];
        float ai = ei[base + idx];
        unsigned short arh, arl, aih, ail;
        bfsplit(ar, arh, arl);
        bfsplit(ai, aih, ail);
        AbfHi[base + idx] = (unsigned int)arh | ((unsigned int)aih << 16);
        AbfLo[base + idx] = (unsigned int)arl | ((unsigned int)ail << 16);
    }
}

// ---------------------------------------------------------------------------
// Kernel 1b: convB — x -> split-bf16 Bre (Bim derived in-register in e_mfma).
// ---------------------------------------------------------------------------
__global__ void convB_kernel(const float* __restrict__ xr, const float* __restrict__ xi,
                             unsigned int* __restrict__ BreHi, unsigned int* __restrict__ BreLo) {
    int bid = blockIdx.x;                 // 256 = 32 bm x 8 Dg
    int bm = bid >> 3;
    int Dg = bid & 7;
    int D0 = Dg * 16;
    int tid = threadIdx.x;

    __shared__ float sxr[16][257];
    __shared__ float sxi[16][257];

    const float* xrp = xr + (size_t)bm * DD * NN;
    const float* xip = xi + (size_t)bm * DD * NN;
#pragma unroll
    for (int it = 0; it < 16; ++it) {
        int i2 = tid + it * 256;
        int r = i2 >> 8, c = i2 & 255;
        sxr[r][c] = xrp[(size_t)(D0 + r) * NN + c];
        sxi[r][c] = xip[(size_t)(D0 + r) * NN + c];
    }
    __syncthreads();

    int n = tid;
    unsigned int reh[16], rel_[16];
#pragma unroll
    for (int d = 0; d < 16; ++d) {
        float br = sxr[d][n];
        float bi = sxi[d][n];
        unsigned short brh, brl, bih, bil;
        bfsplit(br, brh, brl);
        bfsplit(bi, bih, bil);
        reh[d]  = (unsigned int)brh | ((unsigned int)(bih ^ 0x8000) << 16);
        rel_[d] = (unsigned int)brl | ((unsigned int)(bil ^ 0x8000) << 16);
    }
    size_t ob = (size_t)bm * 32768 + (size_t)n * 128 + D0;
#pragma unroll
    for (int w = 0; w < 4; ++w) {
        ((uint4*)(BreHi + ob))[w] = make_uint4(reh[4*w], reh[4*w+1], reh[4*w+2], reh[4*w+3]);
        ((uint4*)(BreLo + ob))[w] = make_uint4(rel_[4*w], rel_[4*w+1], rel_[4*w+2], rel_[4*w+3]);
    }
}

// ---------------------------------------------------------------------------
// Kernel 1c (MFMA v3, t-merged + FUSED Ea/Kb emission):
// block = (pair, h) computes all 3 t planes. Epilogue:
//   t=0 -> E float2 (for qe) + Ea split-bf16 fragment-major (for a_mfma)
//   t=1 -> Kb split-bf16 fragment-major only (K float2 never needed)
//   t=2 -> E float2 (V for res)
// Fragment-major: short off = bh*32768 + ((r*4+ks)*64 + lane)*8, ks=m.
// Wave write = 64 lanes x 16B contiguous (coalesced); a_mfma reads same.
// ---------------------------------------------------------------------------
__global__ __launch_bounds__(256, 1)
void e_mfma_kernel(const unsigned short* __restrict__ AbfHi,
                   const unsigned short* __restrict__ AbfLo,
                   const unsigned short* __restrict__ BreHi,
                   const unsigned short* __restrict__ BreLo,
                   float2* __restrict__ E,
                   unsigned int* __restrict__ EaHi, unsigned int* __restrict__ EaLo,
                   unsigned int* __restrict__ KbHi, unsigned int* __restrict__ KbLo) {
    int bid = blockIdx.x;                 // 256 = 8 xcd x 32 idx
    int xcd = bid & 7;
    int idx = bid >> 3;                   // 0..31
    int pair = xcd * 4 + (idx & 3);       // b*MM+m (XCD-pinned B panels)
    int h = idx >> 2;                     // 0..7
    int b = pair >> 2, m = pair & 3;
    int tid = threadIdx.x;
    int wav = tid >> 6, lane = tid & 63;
    int lo = lane & 15, hi = lane >> 4;

    const unsigned short* AH[3];
    const unsigned short* AL[3];
#pragma unroll
    for (int t = 0; t < 3; ++t) {
        size_t aoff = ((size_t)((t * MM + m) * NHH + h)) * QDD * 256;
        AH[t] = AbfHi + aoff;
        AL[t] = AbfLo + aoff;
    }
    size_t boff = (size_t)pair * 256 * 256;
    const unsigned short* BrH = BreHi + boff;
    const unsigned short* BrL = BreLo + boff;

    f32x4 accRe[3][4], accIm[3][4];
#pragma unroll
    for (int t = 0; t < 3; ++t)
#pragma unroll
        for (int nt = 0; nt < 4; ++nt) {
            accRe[t][nt] = (f32x4)(0.f);
            accIm[t][nt] = (f32x4)(0.f);
        }

#pragma unroll
    for (int ks = 0; ks < 8; ++ks) {
        int k0 = ks * 32;
        int arow = lo * 256 + k0 + hi * 8;
        bf16x8 aH[3], aL[3];
#pragma unroll
        for (int t = 0; t < 3; ++t) {
            aH[t] = *(const bf16x8*)(AH[t] + arow);
            aL[t] = *(const bf16x8*)(AL[t] + arow);
        }
#pragma unroll
        for (int nt = 0; nt < 4; ++nt) {
            int n0 = (wav * 4 + nt) * 16;
            size_t brow = (size_t)(n0 + lo) * 256 + k0 + hi * 8;
            bf16x8 brh = *(const bf16x8*)(BrH + brow);
            bf16x8 brl = *(const bf16x8*)(BrL + brow);
            bf16x8 bih = derive_im(brh);
            bf16x8 bil = derive_im(brl);
#pragma unroll
            for (int t = 0; t < 3; ++t) {
                accRe[t][nt] = __builtin_amdgcn_mfma_f32_16x16x32_bf16(aH[t], brh, accRe[t][nt], 0, 0, 0);
                accRe[t][nt] = __builtin_amdgcn_mfma_f32_16x16x32_bf16(aH[t], brl, accRe[t][nt], 0, 0, 0);
                accRe[t][nt] = __builtin_amdgcn_mfma_f32_16x16x32_bf16(aL[t], brh, accRe[t][nt], 0, 0, 0);
                accIm[t][nt] = __builtin_amdgcn_mfma_f32_16x16x32_bf16(aH[t], bih, accIm[t][nt], 0, 0, 0);
                accIm[t][nt] = __builtin_amdgcn_mfma_f32_16x16x32_bf16(aH[t], bil, accIm[t][nt], 0, 0, 0);
                accIm[t][nt] = __builtin_amdgcn_mfma_f32_16x16x32_bf16(aL[t], bih, accIm[t][nt], 0, 0, 0);
            }
        }
    }

    int bh = b * NHH + h;
    // t=0: E float2 + Ea fragments ; t=1: Kb fragments ; t=2: E float2.
#pragma unroll
    for (int t = 0; t < 3; ++t) {
        size_t ebase = (size_t)((((t * BB + b) * MM + m) * NHH + h) * QDD) * NN;
#pragma unroll
        for (int nt = 0; nt < 4; ++nt) {
            int n0 = (wav * 4 + nt) * 16;
            if (t != 1) {
#pragma unroll
                for (int reg = 0; reg < 4; ++reg) {
                    int q = hi * 4 + reg;
                    E[ebase + (size_t)q * NN + n0 + lo] =
                        make_float2(accRe[t][nt][reg], accIm[t][nt][reg]);
                }
            }
            if (t < 2) {
                unsigned int hiU[4], loU[4];
#pragma unroll
                for (int reg = 0; reg < 4; ++reg) {
                    unsigned short rh, rl, ih, il;
                    bfsplit(accRe[t][nt][reg], rh, rl);
                    bfsplit(accIm[t][nt][reg], ih, il);
                    hiU[reg] = (unsigned int)rh | ((unsigned int)ih << 16);
                    loU[reg] = (unsigned int)rl | ((unsigned int)il << 16);
                }
                // r = wav*4+nt, ks = m, lane; uint off = (((r*4+ks)*64)+lane)*4
                size_t fo = (size_t)bh * 16384 + (size_t)(((wav * 4 + nt) * 4 + m) * 64 + lane) * 4;
                unsigned int* tH = (t == 0) ? EaHi : KbHi;
                unsigned int* tL = (t == 0) ? EaLo : KbLo;
                *(uint4*)(tH + fo) = make_uint4(hiU[0], hiU[1], hiU[2], hiU[3]);
                *(uint4*)(tL + fo) = make_uint4(loU[0], loU[1], loU[2], loU[3]);
            }
        }
    }
}

// ---------------------------------------------------------------------------
// Kernel 2: QE[b,m,h,i] = sum_q conj(E0[b,m,h,q,i]) * enc0[m,h,q]
// ---------------------------------------------------------------------------
__global__ void qe_kernel(const float2* __restrict__ E,
                          const float* __restrict__ encr, const float* __restrict__ enci,
                          float2* __restrict__ QE) {
    int bid = blockIdx.x;                 // (b*MM+m)*NHH + h
    int i = threadIdx.x;
    const float2* e0 = E + (size_t)(bid) * QDD * NN;   // t=0 plane
    int h = bid & 7;
    int bm = bid >> 3;
    int m = bm & 3;
    int encbase = (m * NHH + h) * QDD;    // enc[0,m,h,0,q,0]
    float ar = 0.f, ai = 0.f;
#pragma unroll
    for (int q = 0; q < QDD; ++q) {
        float2 e = e0[q * NN + i];
        float cr = encr[encbase + q], ci = enci[encbase + q];
        // conj(e) * enc
        ar = fmaf(e.x, cr, fmaf( e.y, ci, ar));
        ai = fmaf(e.x, ci, fmaf(-e.y, cr, ai));
    }
    QE[(size_t)bid * NN + i] = make_float2(ar, ai);
}

// ---------------------------------------------------------------------------
// Kernel 3 (a_mfma v3, coalesced fragment-major reads):
// Scores[bh][i][j] = sum_k Ea[i][k]*Kb[j][k] (K=128 real) + pe epilogue.
// Block = (bh, iquad); wave = i-tile; 16 j-tiles per wave.
// Fragment loads are 64-lane x 16B contiguous (1KB coalesced).
// ---------------------------------------------------------------------------
__global__ __launch_bounds__(256, 1)
void a_mfma_kernel(const unsigned short* __restrict__ EaHi,
                   const unsigned short* __restrict__ EaLo,
                   const unsigned short* __restrict__ KbHi,
                   const unsigned short* __restrict__ KbLo,
                   const float2* __restrict__ QE,
                   const float2* __restrict__ peIJ,
                   float2* __restrict__ Scores) {
    int bid = blockIdx.x;                 // 256 = 8 xcd x 32 idx
    int xcd = bid & 7;
    int idx = bid >> 3;                   // 0..31
    int bh = xcd * 8 + (idx & 7);         // K-panel XCD-pinned
    int iquad = idx >> 3;                 // 0..3
    int b = bh >> 3, h = bh & 7;
    int tid = threadIdx.x;
    int wav = tid >> 6, lane = tid & 63;
    int lo = lane & 15, hi = lane >> 4;
    int it = iquad * 4 + wav;             // this wave's i-tile (0..15)

    const unsigned short* EaH = EaHi + (size_t)bh * 32768;
    const unsigned short* EaL = EaLo + (size_t)bh * 32768;
    const unsigned short* KbH = KbHi + (size_t)bh * 32768;
    const unsigned short* KbL = KbLo + (size_t)bh * 32768;

    f32x4 accRe[16], accIm[16];
#pragma unroll
    for (int nt = 0; nt < 16; ++nt) { accRe[nt] = (f32x4)(0.f); accIm[nt] = (f32x4)(0.f); }

#pragma unroll
    for (int ks = 0; ks < 4; ++ks) {
        size_t arow = (size_t)((it * 4 + ks) * 64 + lane) * 8;   // coalesced
        bf16x8 aH = *(const bf16x8*)(EaH + arow);
        bf16x8 aL = *(const bf16x8*)(EaL + arow);
#pragma unroll
        for (int nt = 0; nt < 16; ++nt) {
            size_t brow = (size_t)((nt * 4 + ks) * 64 + lane) * 8;  // coalesced
            bf16x8 brh = *(const bf16x8*)(KbH + brow);
            bf16x8 brl = *(const bf16x8*)(KbL + brow);
            bf16x8 bih = derive_im2(brh);
            bf16x8 bil = derive_im2(brl);
            accRe[nt] = __builtin_amdgcn_mfma_f32_16x16x32_bf16(aH, brh, accRe[nt], 0, 0, 0);
            accRe[nt] = __builtin_amdgcn_mfma_f32_16x16x32_bf16(aH, brl, accRe[nt], 0, 0, 0);
            accRe[nt] = __builtin_amdgcn_mfma_f32_16x16x32_bf16(aL, brh, accRe[nt], 0, 0, 0);
            accIm[nt] = __builtin_amdgcn_mfma_f32_16x16x32_bf16(aH, bih, accIm[nt], 0, 0, 0);
            accIm[nt] = __builtin_amdgcn_mfma_f32_16x16x32_bf16(aH, bil, accIm[nt], 0, 0, 0);
            accIm[nt] = __builtin_amdgcn_mfma_f32_16x16x32_bf16(aL, bih, accIm[nt], 0, 0, 0);
        }
    }

    // epilogue: + sum_m QE[b,m,h,i]*pe[m,i,j]; write Scores.
    float2 qe[MM][4];
#pragma unroll
    for (int m = 0; m < MM; ++m)
#pragma unroll
        for (int reg = 0; reg < 4; ++reg) {
            int i = it * 16 + hi * 4 + reg;
            qe[m][reg] = QE[(size_t)((b * MM + m) * NHH + h) * NN + i];
        }

#pragma unroll
    for (int nt = 0; nt < 16; ++nt) {
#pragma unroll
        for (int reg = 0; reg < 4; ++reg) {
            int i = it * 16 + hi * 4 + reg;
            int j = nt * 16 + lo;
            float ar = accRe[nt][reg];
            float ai = accIm[nt][reg];
#pragma unroll
            for (int m = 0; m < MM; ++m) {
                float2 p = peIJ[(size_t)(m * NN + i) * NN + j];
                float2 e1 = qe[m][reg];
                ar = fmaf(e1.x, p.x, fmaf(-e1.y, p.y, ar));
                ai = fmaf(e1.x, p.y, fmaf( e1.y, p.x, ai));
            }
            Scores[(size_t)(bh * NN + i) * NN + j] = make_float2(ar, ai);
        }
    }
}

// ---------------------------------------------------------------------------
// Kernel 4: row softmax of |A|/4 over j; writes TRANSPOSED Aw:
//   AwT[(bh*N + j)*N + i]
// ---------------------------------------------------------------------------
__global__ void softmax_kernel(const float2* __restrict__ A, float* __restrict__ AwT) {
    int row = blockIdx.x;                 // (b*NHH+h)*NN + i
    int j = threadIdx.x;
    float2 a = A[(size_t)row * NN + j];
    float v = sqrtf(fmaf(a.x, a.x, a.y * a.y)) * 0.25f;

    __shared__ float smax[4];
    __shared__ float ssum[4];
    int lane = threadIdx.x & 63;
    int wid  = threadIdx.x >> 6;

    float mv = v;
#pragma unroll
    for (int off = 32; off > 0; off >>= 1) mv = fmaxf(mv, __shfl_xor(mv, off));
    if (lane == 0) smax[wid] = mv;
    __syncthreads();
    float mx = fmaxf(fmaxf(smax[0], smax[1]), fmaxf(smax[2], smax[3]));

    float e = expf(v - mx);
    float sv = e;
#pragma unroll
    for (int off = 32; off > 0; off >>= 1) sv += __shfl_xor(sv, off);
    if (lane == 0) ssum[wid] = sv;
    __syncthreads();
    float sum = ssum[0] + ssum[1] + ssum[2] + ssum[3];

    float aw = e / sum;
    int bh = row >> 8;
    int i  = row & 255;
    AwT[(size_t)(bh * NN + j) * NN + i] = aw;
}

// ---------------------------------------------------------------------------
// Kernel 5 (qh-split + XCD swizzle): 512 blocks = 64 idx x 8 xcd.
// ---------------------------------------------------------------------------
__global__ __launch_bounds__(512)
void res_kernel(const float2* __restrict__ E, const float* __restrict__ AwT,
                const float2* __restrict__ peT,
                const float* __restrict__ encr, const float* __restrict__ enci,
                float2* __restrict__ Res) {
    int bid = blockIdx.x;
    int xcd = bid & 7;
    int idx = bid >> 3;                   // 0..63
    int bh = xcd * 8 + (idx & 7);         // b*NHH+h
    int mqh = idx >> 3;                   // 0..7
    int m  = mqh >> 1;
    int qh = mqh & 1;
    int h = bh & 7;
    int b = bh >> 3;
    int i = threadIdx.x & 255;
    int g = threadIdx.x >> 8;             // j-half 0/1

    __shared__ float2 sv[8][NN];          // 16 KB: this qh's 8 V rows
    __shared__ float2 spA[NN][9];         // 18 KB: g=1 partials (8 acc + PA)
    __shared__ float2 senc[8];

    const float2* V = E + ((size_t)(((2 * BB + b) * MM + m) * NHH + h) * QDD + qh * 8) * NN;
    for (int i2 = threadIdx.x; i2 < 8 * NN; i2 += 512) sv[i2 >> 8][i2 & 255] = V[i2];
    if (threadIdx.x < 8) {
        int eb = ((MM + m) * NHH + h) * QDD + qh * 8 + threadIdx.x;   // enc[1,...]
        senc[threadIdx.x] = make_float2(encr[eb], enci[eb]);
    }
    __syncthreads();

    float accr[8], acci[8];
#pragma unroll
    for (int q = 0; q < 8; ++q) { accr[q] = 0.f; acci[q] = 0.f; }
    float par = 0.f, pai = 0.f;

    const float*  awp = AwT + (size_t)((b * NHH + h) * NN) * NN + i;
    const float2* pep = peT + (size_t)(m * NN) * NN + i;
    int j0 = g * (NN / 2);
    for (int j = j0; j < j0 + NN / 2; ++j) {
        float aw  = awp[(size_t)j * NN];      // coalesced over i
        float2 p  = pep[(size_t)j * NN];      // coalesced over i
        par = fmaf(p.x, aw, par);
        pai = fmaf(p.y, aw, pai);
#pragma unroll
        for (int q = 0; q < 8; ++q) {
            float2 vv = sv[q][j];             // wave-uniform -> broadcast
            accr[q] = fmaf(vv.x, aw, accr[q]);
            acci[q] = fmaf(vv.y, aw, acci[q]);
        }
    }

    if (g == 1) {
#pragma unroll
        for (int q = 0; q < 8; ++q) spA[i][q] = make_float2(accr[q], acci[q]);
        spA[i][8] = make_float2(par, pai);
    }
    __syncthreads();
    if (g == 0) {
#pragma unroll
        for (int q = 0; q < 8; ++q) {
            float2 o = spA[i][q];
            accr[q] += o.x; acci[q] += o.y;
        }
        float2 o = spA[i][8];
        par += o.x; pai += o.y;

        float2* rp = Res + ((size_t)((b * MM + m) * KO + h * QDD + qh * 8)) * NN + i;
#pragma unroll
        for (int q = 0; q < 8; ++q) {
            float2 e1 = senc[q];
            float rr = accr[q] + e1.x * par - e1.y * pai;
            float ri = acci[q] + e1.x * pai + e1.y * par;
            rp[(size_t)q * NN] = make_float2(rr, ri);
        }
    }
}

// ---------------------------------------------------------------------------
// Kernel 6 (DTILE=8 + XCD swizzle): out[b,m,D,n] = sum_k w_out*res.
// ---------------------------------------------------------------------------
__global__ void out_kernel(const float2* __restrict__ Res,
                           const float* __restrict__ wor, const float* __restrict__ woi,
                           float* __restrict__ out) {
    int bid = blockIdx.x;
    int xcd = bid & 7;
    int idx = bid >> 3;                   // 0..63
    int bm = xcd * 4 + (idx & 3);         // b*MM+m, 0..31
    int dt = idx >> 2;                    // 0..15
    int n = threadIdx.x;
    int D0 = dt * DTILE;
    int m = bm & 3;

    __shared__ float2 sw[DTILE][KO];      // 8 KB
    for (int i2 = threadIdx.x; i2 < DTILE * KO; i2 += 256) {
        int d = i2 >> 7, k = i2 & 127;
        int wb = (m * DD + D0 + d) * KO + k;
        sw[d][k] = make_float2(wor[wb], woi[wb]);
    }
    __syncthreads();

    const float2* rp = Res + (size_t)(bm * KO) * NN + n;
    float ar[DTILE], ai[DTILE];
#pragma unroll
    for (int d = 0; d < DTILE; ++d) { ar[d] = 0.f; ai[d] = 0.f; }

    for (int k = 0; k < KO; ++k) {
        float2 r = rp[(size_t)k * NN];    // coalesced
#pragma unroll
        for (int d = 0; d < DTILE; ++d) {
            float2 w = sw[d][k];          // broadcast
            ar[d] = fmaf(w.x, r.x, fmaf(-w.y, r.y, ar[d]));
            ai[d] = fmaf(w.x, r.y, fmaf( w.y, r.x, ai[d]));
        }
    }
#pragma unroll
    for (int d = 0; d < DTILE; ++d) {
        size_t ob = (size_t)(bm * DD + D0 + d) * NN + n;
        out[ob] = ar[d];
        out[(size_t)BB * MM * DD * NN + ob] = ai[d];
    }
}

// ---------------------------------------------------------------------------
extern "C" void kernel_launch(void* const* d_in, const int* in_sizes, int n_in,
                              void* d_out, int out_size, void* d_ws, size_t ws_size,
                              hipStream_t stream) {
    (void)in_sizes; (void)n_in; (void)out_size; (void)ws_size;

    const float* x_re   = (const float*)d_in[0];
    const float* x_im   = (const float*)d_in[1];
    const float* emb_re = (const float*)d_in[2];
    const float* emb_im = (const float*)d_in[3];
    const float* enc_re = (const float*)d_in[4];
    const float* enc_im = (const float*)d_in[5];
    const float* out_re = (const float*)d_in[6];
    const float* out_im = (const float*)d_in[7];
    float* out = (float*)d_out;

    // Workspace layout (floats). Total ~155.7 MB.
    float* ws = (float*)d_ws;
    size_t off = 0;
    float2* peIJ = (float2*)(ws + off); off += (size_t)MM * NN * NN * 2;          // 524288
    float2* peT  = (float2*)(ws + off); off += (size_t)MM * NN * NN * 2;          // 524288
    float2* E    = (float2*)(ws + off); off += (size_t)3 * BB * MM * NHH * QDD * NN * 2; // 25165824
    float2* QE   = (float2*)(ws + off); off += (size_t)BB * MM * NHH * NN * 2;    // 131072
    float2* A    = (float2*)(ws + off); off += (size_t)BB * NHH * NN * NN * 2;    // 8388608 fl
    float*  AwT  = (float*)(ws + off);  off += (size_t)BB * NHH * NN * NN;        // 4194304 fl

    // Region plan:
    //  1) convA/convB stage Abf/Bre in A region; e_mfma reads them ->
    //     writes E (t0,t2 float2) + Ea/Kb fragments into AwT region.
    //  2) qe reads E t0.
    //  3) a_mfma reads Ea/Kb(AwT region) -> Scores over FULL A region.
    //  4) softmax reads Scores(A) -> writes AwT (Ea/Kb dead).
    //  5) res reads AwT + V(E t2) -> Res into A region start (Scores dead).
    unsigned int* AbfHi = (unsigned int*)A;
    unsigned int* AbfLo = AbfHi + (size_t)96 * QDD * DD;
    unsigned int* BreHi = AbfLo + (size_t)96 * QDD * DD;
    unsigned int* BreLo = BreHi + (size_t)32 * 256 * 128;

    unsigned int* EaHi = (unsigned int*)AwT;                      // 4 x 1048576 uints
    unsigned int* EaLo = EaHi + (size_t)64 * 16384;               //  = 16.78MB exact
    unsigned int* KbHi = EaLo + (size_t)64 * 16384;
    unsigned int* KbLo = KbHi + (size_t)64 * 16384;

    float2* Scores = A;   // full 33.5MB A region
    float2* Res    = A;   // first 8.4MB of A region, after Scores is dead

    pe_kernel<<<MM * NN, 256, 0, stream>>>(peIJ, peT);
    convA_kernel<<<96, 256, 0, stream>>>(emb_re, emb_im, AbfHi, AbfLo);
    convB_kernel<<<256, 256, 0, stream>>>(x_re, x_im, BreHi, BreLo);
    e_mfma_kernel<<<256, 256, 0, stream>>>(
        (const unsigned short*)AbfHi, (const unsigned short*)AbfLo,
        (const unsigned short*)BreHi, (const unsigned short*)BreLo, E,
        EaHi, EaLo, KbHi, KbLo);
    qe_kernel<<<BB * MM * NHH, 256, 0, stream>>>(E, enc_re, enc_im, QE);
    a_mfma_kernel<<<256, 256, 0, stream>>>(
        (const unsigned short*)EaHi, (const unsigned short*)EaLo,
        (const unsigned short*)KbHi, (const unsigned short*)KbLo,
        QE, peIJ, Scores);
    softmax_kernel<<<BB * NHH * NN, 256, 0, stream>>>(Scores, AwT);
    res_kernel<<<BB * MM * NHH * 2, 512, 0, stream>>>(E, AwT, peT, enc_re, enc_im, Res);
    out_kernel<<<BB * MM * (DD / DTILE), 256, 0, stream>>>(Res, out_re, out_im, out);
}

// Round 33
// 157.380 us; speedup vs baseline: 1.2095x; 1.0419x over previous
//
#include <hip/hip_runtime.h>
#include <math.h>

// Problem constants (from reference)
#define BB   8      // batch
#define MM   4      // MAXM
#define DD   128    // DIM
#define NHH  8      // heads
#define QDD  16     // head dim
#define NN   256    // H*W
#define KO   128    // NH*QD
#define DTILE 8     // D-rows per out_kernel block

typedef float v2f __attribute__((ext_vector_type(2)));
#define PKFMA(a, b, c) __builtin_elementwise_fma((a), (b), (c))

typedef __attribute__((ext_vector_type(8))) short bf16x8;   // 8 bf16 (4 VGPR)
typedef __attribute__((ext_vector_type(4))) float f32x4;    // MFMA acc

__device__ inline unsigned short f2bf(float f) {            // RNE float->bf16
    union { float f; unsigned u; } v; v.f = f;
    unsigned r = v.u + 0x7FFF + ((v.u >> 16) & 1);
    return (unsigned short)(r >> 16);
}
__device__ inline float bf2f(unsigned short h) {
    union { unsigned u; float f; } v; v.u = ((unsigned)h) << 16;
    return v.f;
}
// split x = hi + lo (both bf16)
__device__ inline void bfsplit(float x, unsigned short& hi, unsigned short& lo) {
    hi = f2bf(x);
    lo = f2bf(x - bf2f(hi));
}
// e_mfma: (br | -bi<<16) -> (bi | br<<16)
__device__ inline bf16x8 derive_im(bf16x8 v) {
    union { bf16x8 v; unsigned u[4]; } in, out;
    in.v = v;
#pragma unroll
    for (int w = 0; w < 4; ++w)
        out.u[w] = ((in.u[w] >> 16) ^ 0x8000u) | (in.u[w] << 16);
    return out.v;
}
// a_mfma: (kx | ky<<16) -> (ky | (-kx)<<16)
__device__ inline bf16x8 derive_im2(bf16x8 v) {
    union { bf16x8 v; unsigned u[4]; } in, out;
    in.v = v;
#pragma unroll
    for (int w = 0; w < 4; ++w)
        out.u[w] = (in.u[w] >> 16) | ((in.u[w] ^ 0x8000u) << 16);
    return out.v;
}

// ---------------------------------------------------------------------------
// Kernel 0 (trig-free): pe[m,i,j] = exp(i*m*theta) = ((dx+i*dy)/r)^m.
// ---------------------------------------------------------------------------
__global__ void pe_kernel(float2* __restrict__ peIJ, float2* __restrict__ peT) {
    int bid = blockIdx.x;           // m*N + i
    int m = bid >> 8;
    int i = bid & 255;
    int j = threadIdx.x;
    float dy = (float)((j >> 4) - (i >> 4));
    float dx = (float)((j & 15) - (i & 15));
    float r2 = dx * dx + dy * dy;
    float c1 = 1.f, s1 = 0.f;
    if (r2 > 0.f) {
        float rinv = rsqrtf(r2);
        c1 = dx * rinv; s1 = dy * rinv;
    }
    float c = 1.f, s = 0.f;
    for (int k = 0; k < m; ++k) {   // m is block-uniform (0..3)
        float nc = c * c1 - s * s1;
        s = c * s1 + s * c1;
        c = nc;
    }
    peIJ[(m * NN + i) * NN + j] = make_float2(c, s);
    peT[(m * NN + j) * NN + i] = make_float2(c, s);
}

// ---------------------------------------------------------------------------
// Kernel 1a: convA — emb -> A' split-bf16 (k = 2D|2D+1 = ar|ai).
// ---------------------------------------------------------------------------
__global__ void convA_kernel(const float* __restrict__ er, const float* __restrict__ ei,
                             unsigned int* __restrict__ AbfHi, unsigned int* __restrict__ AbfLo) {
    int tmh = blockIdx.x;                 // 0..95
    int base = tmh * QDD * DD;
#pragma unroll
    for (int it = 0; it < 8; ++it) {
        int idx = threadIdx.x + it * 256;  // q*128+D
        float ar = er[base + idx];
        float ai = ei[base + idx];
        unsigned short arh, arl, aih, ail;
        bfsplit(ar, arh, arl);
        bfsplit(ai, aih, ail);
        AbfHi[base + idx] = (unsigned int)arh | ((unsigned int)aih << 16);
        AbfLo[base + idx] = (unsigned int)arl | ((unsigned int)ail << 16);
    }
}

// ---------------------------------------------------------------------------
// Kernel 1b: convB — x -> split-bf16 Bre (Bim derived in-register in e_mfma).
// ---------------------------------------------------------------------------
__global__ void convB_kernel(const float* __restrict__ xr, const float* __restrict__ xi,
                             unsigned int* __restrict__ BreHi, unsigned int* __restrict__ BreLo) {
    int bid = blockIdx.x;                 // 256 = 32 bm x 8 Dg
    int bm = bid >> 3;
    int Dg = bid & 7;
    int D0 = Dg * 16;
    int tid = threadIdx.x;

    __shared__ float sxr[16][257];
    __shared__ float sxi[16][257];

    const float* xrp = xr + (size_t)bm * DD * NN;
    const float* xip = xi + (size_t)bm * DD * NN;
#pragma unroll
    for (int it = 0; it < 16; ++it) {
        int i2 = tid + it * 256;
        int r = i2 >> 8, c = i2 & 255;
        sxr[r][c] = xrp[(size_t)(D0 + r) * NN + c];
        sxi[r][c] = xip[(size_t)(D0 + r) * NN + c];
    }
    __syncthreads();

    int n = tid;
    unsigned int reh[16], rel_[16];
#pragma unroll
    for (int d = 0; d < 16; ++d) {
        float br = sxr[d][n];
        float bi = sxi[d][n];
        unsigned short brh, brl, bih, bil;
        bfsplit(br, brh, brl);
        bfsplit(bi, bih, bil);
        reh[d]  = (unsigned int)brh | ((unsigned int)(bih ^ 0x8000) << 16);
        rel_[d] = (unsigned int)brl | ((unsigned int)(bil ^ 0x8000) << 16);
    }
    size_t ob = (size_t)bm * 32768 + (size_t)n * 128 + D0;
#pragma unroll
    for (int w = 0; w < 4; ++w) {
        ((uint4*)(BreHi + ob))[w] = make_uint4(reh[4*w], reh[4*w+1], reh[4*w+2], reh[4*w+3]);
        ((uint4*)(BreLo + ob))[w] = make_uint4(rel_[4*w], rel_[4*w+1], rel_[4*w+2], rel_[4*w+3]);
    }
}

// ---------------------------------------------------------------------------
// Kernel 1c (MFMA v4, t-merged + fused Ea/Kb emission + n-split for 2x
// occupancy): 512 blocks = 8 xcd x 64 idx; block = (pair, h, nhalf).
// Each wave computes 2 n-tiles x 3 t planes; acc = 48 VGPR.
// ---------------------------------------------------------------------------
__global__ __launch_bounds__(256, 2)
void e_mfma_kernel(const unsigned short* __restrict__ AbfHi,
                   const unsigned short* __restrict__ AbfLo,
                   const unsigned short* __restrict__ BreHi,
                   const unsigned short* __restrict__ BreLo,
                   float2* __restrict__ E,
                   unsigned int* __restrict__ EaHi, unsigned int* __restrict__ EaLo,
                   unsigned int* __restrict__ KbHi, unsigned int* __restrict__ KbLo) {
    int bid = blockIdx.x;                 // 512 = 8 xcd x 64 idx
    int xcd = bid & 7;
    int idx = bid >> 3;                   // 0..63
    int pair = xcd * 4 + (idx & 3);       // b*MM+m (XCD-pinned B panels)
    int h = (idx >> 2) & 7;               // 0..7
    int nhalf = idx >> 5;                 // 0..1
    int b = pair >> 2, m = pair & 3;
    int tid = threadIdx.x;
    int wav = tid >> 6, lane = tid & 63;
    int lo = lane & 15, hi = lane >> 4;

    const unsigned short* AH[3];
    const unsigned short* AL[3];
#pragma unroll
    for (int t = 0; t < 3; ++t) {
        size_t aoff = ((size_t)((t * MM + m) * NHH + h)) * QDD * 256;
        AH[t] = AbfHi + aoff;
        AL[t] = AbfLo + aoff;
    }
    size_t boff = (size_t)pair * 256 * 256;
    const unsigned short* BrH = BreHi + boff;
    const unsigned short* BrL = BreLo + boff;

    f32x4 accRe[3][2], accIm[3][2];
#pragma unroll
    for (int t = 0; t < 3; ++t)
#pragma unroll
        for (int nt = 0; nt < 2; ++nt) {
            accRe[t][nt] = (f32x4)(0.f);
            accIm[t][nt] = (f32x4)(0.f);
        }

#pragma unroll
    for (int ks = 0; ks < 8; ++ks) {
        int k0 = ks * 32;
        int arow = lo * 256 + k0 + hi * 8;
        bf16x8 aH[3], aL[3];
#pragma unroll
        for (int t = 0; t < 3; ++t) {
            aH[t] = *(const bf16x8*)(AH[t] + arow);
            aL[t] = *(const bf16x8*)(AL[t] + arow);
        }
#pragma unroll
        for (int nt = 0; nt < 2; ++nt) {
            int n0 = nhalf * 128 + (wav * 2 + nt) * 16;
            size_t brow = (size_t)(n0 + lo) * 256 + k0 + hi * 8;
            bf16x8 brh = *(const bf16x8*)(BrH + brow);
            bf16x8 brl = *(const bf16x8*)(BrL + brow);
            bf16x8 bih = derive_im(brh);
            bf16x8 bil = derive_im(brl);
#pragma unroll
            for (int t = 0; t < 3; ++t) {
                accRe[t][nt] = __builtin_amdgcn_mfma_f32_16x16x32_bf16(aH[t], brh, accRe[t][nt], 0, 0, 0);
                accRe[t][nt] = __builtin_amdgcn_mfma_f32_16x16x32_bf16(aH[t], brl, accRe[t][nt], 0, 0, 0);
                accRe[t][nt] = __builtin_amdgcn_mfma_f32_16x16x32_bf16(aL[t], brh, accRe[t][nt], 0, 0, 0);
                accIm[t][nt] = __builtin_amdgcn_mfma_f32_16x16x32_bf16(aH[t], bih, accIm[t][nt], 0, 0, 0);
                accIm[t][nt] = __builtin_amdgcn_mfma_f32_16x16x32_bf16(aH[t], bil, accIm[t][nt], 0, 0, 0);
                accIm[t][nt] = __builtin_amdgcn_mfma_f32_16x16x32_bf16(aL[t], bih, accIm[t][nt], 0, 0, 0);
            }
        }
    }

    int bh = b * NHH + h;
    // t=0: E float2 + Ea fragments ; t=1: Kb fragments ; t=2: E float2.
#pragma unroll
    for (int t = 0; t < 3; ++t) {
        size_t ebase = (size_t)((((t * BB + b) * MM + m) * NHH + h) * QDD) * NN;
#pragma unroll
        for (int nt = 0; nt < 2; ++nt) {
            int n0 = nhalf * 128 + (wav * 2 + nt) * 16;
            if (t != 1) {
#pragma unroll
                for (int reg = 0; reg < 4; ++reg) {
                    int q = hi * 4 + reg;
                    E[ebase + (size_t)q * NN + n0 + lo] =
                        make_float2(accRe[t][nt][reg], accIm[t][nt][reg]);
                }
            }
            if (t < 2) {
                unsigned int hiU[4], loU[4];
#pragma unroll
                for (int reg = 0; reg < 4; ++reg) {
                    unsigned short rh, rl, ih, il;
                    bfsplit(accRe[t][nt][reg], rh, rl);
                    bfsplit(accIm[t][nt][reg], ih, il);
                    hiU[reg] = (unsigned int)rh | ((unsigned int)ih << 16);
                    loU[reg] = (unsigned int)rl | ((unsigned int)il << 16);
                }
                // r = n0/16, ks = m; uint off = (((r*4+ks)*64)+lane)*4
                int r = n0 >> 4;
                size_t fo = (size_t)bh * 16384 + (size_t)((r * 4 + m) * 64 + lane) * 4;
                unsigned int* tH = (t == 0) ? EaHi : KbHi;
                unsigned int* tL = (t == 0) ? EaLo : KbLo;
                *(uint4*)(tH + fo) = make_uint4(hiU[0], hiU[1], hiU[2], hiU[3]);
                *(uint4*)(tL + fo) = make_uint4(loU[0], loU[1], loU[2], loU[3]);
            }
        }
    }
}

// ---------------------------------------------------------------------------
// Kernel 2: QE[b,m,h,i] = sum_q conj(E0[b,m,h,q,i]) * enc0[m,h,q]
// ---------------------------------------------------------------------------
__global__ void qe_kernel(const float2* __restrict__ E,
                          const float* __restrict__ encr, const float* __restrict__ enci,
                          float2* __restrict__ QE) {
    int bid = blockIdx.x;                 // (b*MM+m)*NHH + h
    int i = threadIdx.x;
    const float2* e0 = E + (size_t)(bid) * QDD * NN;   // t=0 plane
    int h = bid & 7;
    int bm = bid >> 3;
    int m = bm & 3;
    int encbase = (m * NHH + h) * QDD;    // enc[0,m,h,0,q,0]
    float ar = 0.f, ai = 0.f;
#pragma unroll
    for (int q = 0; q < QDD; ++q) {
        float2 e = e0[q * NN + i];
        float cr = encr[encbase + q], ci = enci[encbase + q];
        // conj(e) * enc
        ar = fmaf(e.x, cr, fmaf( e.y, ci, ar));
        ai = fmaf(e.x, ci, fmaf(-e.y, cr, ai));
    }
    QE[(size_t)bid * NN + i] = make_float2(ar, ai);
}

// ---------------------------------------------------------------------------
// Kernel 3 (a_mfma v4, coalesced + j-split for 2x occupancy):
// 512 blocks = 8 xcd x 64 idx; block = (bh, iquad, jhalf); wave = i-tile,
// 8 j-tiles per wave; acc = 64 VGPR.
// ---------------------------------------------------------------------------
__global__ __launch_bounds__(256, 2)
void a_mfma_kernel(const unsigned short* __restrict__ EaHi,
                   const unsigned short* __restrict__ EaLo,
                   const unsigned short* __restrict__ KbHi,
                   const unsigned short* __restrict__ KbLo,
                   const float2* __restrict__ QE,
                   const float2* __restrict__ peIJ,
                   float2* __restrict__ Scores) {
    int bid = blockIdx.x;                 // 512 = 8 xcd x 64 idx
    int xcd = bid & 7;
    int idx = bid >> 3;                   // 0..63
    int bh = xcd * 8 + (idx & 7);         // K-panel XCD-pinned
    int iquad = (idx >> 3) & 3;           // 0..3
    int jhalf = idx >> 5;                 // 0..1
    int b = bh >> 3, h = bh & 7;
    int tid = threadIdx.x;
    int wav = tid >> 6, lane = tid & 63;
    int lo = lane & 15, hi = lane >> 4;
    int it = iquad * 4 + wav;             // this wave's i-tile (0..15)

    const unsigned short* EaH = EaHi + (size_t)bh * 32768;
    const unsigned short* EaL = EaLo + (size_t)bh * 32768;
    const unsigned short* KbH = KbHi + (size_t)bh * 32768;
    const unsigned short* KbL = KbLo + (size_t)bh * 32768;

    f32x4 accRe[8], accIm[8];
#pragma unroll
    for (int nt = 0; nt < 8; ++nt) { accRe[nt] = (f32x4)(0.f); accIm[nt] = (f32x4)(0.f); }

#pragma unroll
    for (int ks = 0; ks < 4; ++ks) {
        size_t arow = (size_t)((it * 4 + ks) * 64 + lane) * 8;   // coalesced
        bf16x8 aH = *(const bf16x8*)(EaH + arow);
        bf16x8 aL = *(const bf16x8*)(EaL + arow);
#pragma unroll
        for (int nt = 0; nt < 8; ++nt) {
            int jt = jhalf * 8 + nt;
            size_t brow = (size_t)((jt * 4 + ks) * 64 + lane) * 8;  // coalesced
            bf16x8 brh = *(const bf16x8*)(KbH + brow);
            bf16x8 brl = *(const bf16x8*)(KbL + brow);
            bf16x8 bih = derive_im2(brh);
            bf16x8 bil = derive_im2(brl);
            accRe[nt] = __builtin_amdgcn_mfma_f32_16x16x32_bf16(aH, brh, accRe[nt], 0, 0, 0);
            accRe[nt] = __builtin_amdgcn_mfma_f32_16x16x32_bf16(aH, brl, accRe[nt], 0, 0, 0);
            accRe[nt] = __builtin_amdgcn_mfma_f32_16x16x32_bf16(aL, brh, accRe[nt], 0, 0, 0);
            accIm[nt] = __builtin_amdgcn_mfma_f32_16x16x32_bf16(aH, bih, accIm[nt], 0, 0, 0);
            accIm[nt] = __builtin_amdgcn_mfma_f32_16x16x32_bf16(aH, bil, accIm[nt], 0, 0, 0);
            accIm[nt] = __builtin_amdgcn_mfma_f32_16x16x32_bf16(aL, bih, accIm[nt], 0, 0, 0);
        }
    }

    // epilogue: + sum_m QE[b,m,h,i]*pe[m,i,j]; write Scores.
    float2 qe[MM][4];
#pragma unroll
    for (int m = 0; m < MM; ++m)
#pragma unroll
        for (int reg = 0; reg < 4; ++reg) {
            int i = it * 16 + hi * 4 + reg;
            qe[m][reg] = QE[(size_t)((b * MM + m) * NHH + h) * NN + i];
        }

#pragma unroll
    for (int nt = 0; nt < 8; ++nt) {
#pragma unroll
        for (int reg = 0; reg < 4; ++reg) {
            int i = it * 16 + hi * 4 + reg;
            int j = (jhalf * 8 + nt) * 16 + lo;
            float ar = accRe[nt][reg];
            float ai = accIm[nt][reg];
#pragma unroll
            for (int m = 0; m < MM; ++m) {
                float2 p = peIJ[(size_t)(m * NN + i) * NN + j];
                float2 e1 = qe[m][reg];
                ar = fmaf(e1.x, p.x, fmaf(-e1.y, p.y, ar));
                ai = fmaf(e1.x, p.y, fmaf( e1.y, p.x, ai));
            }
            Scores[(size_t)(bh * NN + i) * NN + j] = make_float2(ar, ai);
        }
    }
}

// ---------------------------------------------------------------------------
// Kernel 4: row softmax of |A|/4 over j; writes TRANSPOSED Aw:
//   AwT[(bh*N + j)*N + i]
// ---------------------------------------------------------------------------
__global__ void softmax_kernel(const float2* __restrict__ A, float* __restrict__ AwT) {
    int row = blockIdx.x;                 // (b*NHH+h)*NN + i
    int j = threadIdx.x;
    float2 a = A[(size_t)row * NN + j];
    float v = sqrtf(fmaf(a.x, a.x, a.y * a.y)) * 0.25f;

    __shared__ float smax[4];
    __shared__ float ssum[4];
    int lane = threadIdx.x & 63;
    int wid  = threadIdx.x >> 6;

    float mv = v;
#pragma unroll
    for (int off = 32; off > 0; off >>= 1) mv = fmaxf(mv, __shfl_xor(mv, off));
    if (lane == 0) smax[wid] = mv;
    __syncthreads();
    float mx = fmaxf(fmaxf(smax[0], smax[1]), fmaxf(smax[2], smax[3]));

    float e = expf(v - mx);
    float sv = e;
#pragma unroll
    for (int off = 32; off > 0; off >>= 1) sv += __shfl_xor(sv, off);
    if (lane == 0) ssum[wid] = sv;
    __syncthreads();
    float sum = ssum[0] + ssum[1] + ssum[2] + ssum[3];

    float aw = e / sum;
    int bh = row >> 8;
    int i  = row & 255;
    AwT[(size_t)(bh * NN + j) * NN + i] = aw;
}

// ---------------------------------------------------------------------------
// Kernel 5 (qh-split + XCD swizzle): 512 blocks = 64 idx x 8 xcd.
// ---------------------------------------------------------------------------
__global__ __launch_bounds__(512)
void res_kernel(const float2* __restrict__ E, const float* __restrict__ AwT,
                const float2* __restrict__ peT,
                const float* __restrict__ encr, const float* __restrict__ enci,
                float2* __restrict__ Res) {
    int bid = blockIdx.x;
    int xcd = bid & 7;
    int idx = bid >> 3;                   // 0..63
    int bh = xcd * 8 + (idx & 7);         // b*NHH+h
    int mqh = idx >> 3;                   // 0..7
    int m  = mqh >> 1;
    int qh = mqh & 1;
    int h = bh & 7;
    int b = bh >> 3;
    int i = threadIdx.x & 255;
    int g = threadIdx.x >> 8;             // j-half 0/1

    __shared__ float2 sv[8][NN];          // 16 KB: this qh's 8 V rows
    __shared__ float2 spA[NN][9];         // 18 KB: g=1 partials (8 acc + PA)
    __shared__ float2 senc[8];

    const float2* V = E + ((size_t)(((2 * BB + b) * MM + m) * NHH + h) * QDD + qh * 8) * NN;
    for (int i2 = threadIdx.x; i2 < 8 * NN; i2 += 512) sv[i2 >> 8][i2 & 255] = V[i2];
    if (threadIdx.x < 8) {
        int eb = ((MM + m) * NHH + h) * QDD + qh * 8 + threadIdx.x;   // enc[1,...]
        senc[threadIdx.x] = make_float2(encr[eb], enci[eb]);
    }
    __syncthreads();

    float accr[8], acci[8];
#pragma unroll
    for (int q = 0; q < 8; ++q) { accr[q] = 0.f; acci[q] = 0.f; }
    float par = 0.f, pai = 0.f;

    const float*  awp = AwT + (size_t)((b * NHH + h) * NN) * NN + i;
    const float2* pep = peT + (size_t)(m * NN) * NN + i;
    int j0 = g * (NN / 2);
    for (int j = j0; j < j0 + NN / 2; ++j) {
        float aw  = awp[(size_t)j * NN];      // coalesced over i
        float2 p  = pep[(size_t)j * NN];      // coalesced over i
        par = fmaf(p.x, aw, par);
        pai = fmaf(p.y, aw, pai);
#pragma unroll
        for (int q = 0; q < 8; ++q) {
            float2 vv = sv[q][j];             // wave-uniform -> broadcast
            accr[q] = fmaf(vv.x, aw, accr[q]);
            acci[q] = fmaf(vv.y, aw, acci[q]);
        }
    }

    if (g == 1) {
#pragma unroll
        for (int q = 0; q < 8; ++q) spA[i][q] = make_float2(accr[q], acci[q]);
        spA[i][8] = make_float2(par, pai);
    }
    __syncthreads();
    if (g == 0) {
#pragma unroll
        for (int q = 0; q < 8; ++q) {
            float2 o = spA[i][q];
            accr[q] += o.x; acci[q] += o.y;
        }
        float2 o = spA[i][8];
        par += o.x; pai += o.y;

        float2* rp = Res + ((size_t)((b * MM + m) * KO + h * QDD + qh * 8)) * NN + i;
#pragma unroll
        for (int q = 0; q < 8; ++q) {
            float2 e1 = senc[q];
            float rr = accr[q] + e1.x * par - e1.y * pai;
            float ri = acci[q] + e1.x * pai + e1.y * par;
            rp[(size_t)q * NN] = make_float2(rr, ri);
        }
    }
}

// ---------------------------------------------------------------------------
// Kernel 6 (DTILE=8 + XCD swizzle): out[b,m,D,n] = sum_k w_out*res.
// ---------------------------------------------------------------------------
__global__ void out_kernel(const float2* __restrict__ Res,
                           const float* __restrict__ wor, const float* __restrict__ woi,
                           float* __restrict__ out) {
    int bid = blockIdx.x;
    int xcd = bid & 7;
    int idx = bid >> 3;                   // 0..63
    int bm = xcd * 4 + (idx & 3);         // b*MM+m, 0..31
    int dt = idx >> 2;                    // 0..15
    int n = threadIdx.x;
    int D0 = dt * DTILE;
    int m = bm & 3;

    __shared__ float2 sw[DTILE][KO];      // 8 KB
    for (int i2 = threadIdx.x; i2 < DTILE * KO; i2 += 256) {
        int d = i2 >> 7, k = i2 & 127;
        int wb = (m * DD + D0 + d) * KO + k;
        sw[d][k] = make_float2(wor[wb], woi[wb]);
    }
    __syncthreads();

    const float2* rp = Res + (size_t)(bm * KO) * NN + n;
    float ar[DTILE], ai[DTILE];
#pragma unroll
    for (int d = 0; d < DTILE; ++d) { ar[d] = 0.f; ai[d] = 0.f; }

    for (int k = 0; k < KO; ++k) {
        float2 r = rp[(size_t)k * NN];    // coalesced
#pragma unroll
        for (int d = 0; d < DTILE; ++d) {
            float2 w = sw[d][k];          // broadcast
            ar[d] = fmaf(w.x, r.x, fmaf(-w.y, r.y, ar[d]));
            ai[d] = fmaf(w.x, r.y, fmaf( w.y, r.x, ai[d]));
        }
    }
#pragma unroll
    for (int d = 0; d < DTILE; ++d) {
        size_t ob = (size_t)(bm * DD + D0 + d) * NN + n;
        out[ob] = ar[d];
        out[(size_t)BB * MM * DD * NN + ob] = ai[d];
    }
}

// ---------------------------------------------------------------------------
extern "C" void kernel_launch(void* const* d_in, const int* in_sizes, int n_in,
                              void* d_out, int out_size, void* d_ws, size_t ws_size,
                              hipStream_t stream) {
    (void)in_sizes; (void)n_in; (void)out_size; (void)ws_size;

    const float* x_re   = (const float*)d_in[0];
    const float* x_im   = (const float*)d_in[1];
    const float* emb_re = (const float*)d_in[2];
    const float* emb_im = (const float*)d_in[3];
    const float* enc_re = (const float*)d_in[4];
    const float* enc_im = (const float*)d_in[5];
    const float* out_re = (const float*)d_in[6];
    const float* out_im = (const float*)d_in[7];
    float* out = (float*)d_out;

    // Workspace layout (floats). Total ~155.7 MB.
    float* ws = (float*)d_ws;
    size_t off = 0;
    float2* peIJ = (float2*)(ws + off); off += (size_t)MM * NN * NN * 2;          // 524288
    float2* peT  = (float2*)(ws + off); off += (size_t)MM * NN * NN * 2;          // 524288
    float2* E    = (float2*)(ws + off); off += (size_t)3 * BB * MM * NHH * QDD * NN * 2; // 25165824
    float2* QE   = (float2*)(ws + off); off += (size_t)BB * MM * NHH * NN * 2;    // 131072
    float2* A    = (float2*)(ws + off); off += (size_t)BB * NHH * NN * NN * 2;    // 8388608 fl
    float*  AwT  = (float*)(ws + off);  off += (size_t)BB * NHH * NN * NN;        // 4194304 fl

    // Region plan (same as r32, verified):
    //  1) convA/convB stage Abf/Bre in A region; e_mfma reads them ->
    //     writes E (t0,t2 float2) + Ea/Kb fragments into AwT region.
    //  2) qe reads E t0.
    //  3) a_mfma reads Ea/Kb(AwT region) -> Scores over FULL A region.
    //  4) softmax reads Scores(A) -> writes AwT (Ea/Kb dead).
    //  5) res reads AwT + V(E t2) -> Res into A region start (Scores dead).
    unsigned int* AbfHi = (unsigned int*)A;
    unsigned int* AbfLo = AbfHi + (size_t)96 * QDD * DD;
    unsigned int* BreHi = AbfLo + (size_t)96 * QDD * DD;
    unsigned int* BreLo = BreHi + (size_t)32 * 256 * 128;

    unsigned int* EaHi = (unsigned int*)AwT;                      // 4 x 1048576 uints
    unsigned int* EaLo = EaHi + (size_t)64 * 16384;               //  = 16.78MB exact
    unsigned int* KbHi = EaLo + (size_t)64 * 16384;
    unsigned int* KbLo = KbHi + (size_t)64 * 16384;

    float2* Scores = A;   // full 33.5MB A region
    float2* Res    = A;   // first 8.4MB of A region, after Scores is dead

    pe_kernel<<<MM * NN, 256, 0, stream>>>(peIJ, peT);
    convA_kernel<<<96, 256, 0, stream>>>(emb_re, emb_im, AbfHi, AbfLo);
    convB_kernel<<<256, 256, 0, stream>>>(x_re, x_im, BreHi, BreLo);
    e_mfma_kernel<<<512, 256, 0, stream>>>(
        (const unsigned short*)AbfHi, (const unsigned short*)AbfLo,
        (const unsigned short*)BreHi, (const unsigned short*)BreLo, E,
        EaHi, EaLo, KbHi, KbLo);
    qe_kernel<<<BB * MM * NHH, 256, 0, stream>>>(E, enc_re, enc_im, QE);
    a_mfma_kernel<<<512, 256, 0, stream>>>(
        (const unsigned short*)EaHi, (const unsigned short*)EaLo,
        (const unsigned short*)KbHi, (const unsigned short*)KbLo,
        QE, peIJ, Scores);
    softmax_kernel<<<BB * NHH * NN, 256, 0, stream>>>(Scores, AwT);
    res_kernel<<<BB * MM * NHH * 2, 512, 0, stream>>>(E, AwT, peT, enc_re, enc_im, Res);
    out_kernel<<<BB * MM * (DD / DTILE), 256, 0, stream>>>(Res, out_re, out_im, out);
}

// Round 34
// 150.711 us; speedup vs baseline: 1.2631x; 1.0442x over previous
//
#include <hip/hip_runtime.h>
#include <math.h>

// Problem constants (from reference)
#define BB   8      // batch
#define MM   4      // MAXM
#define DD   128    // DIM
#define NHH  8      // heads
#define QDD  16     // head dim
#define NN   256    // H*W
#define KO   128    // NH*QD
#define DTILE 8     // D-rows per out_kernel block

typedef float v2f __attribute__((ext_vector_type(2)));
#define PKFMA(a, b, c) __builtin_elementwise_fma((a), (b), (c))

typedef __attribute__((ext_vector_type(8))) short bf16x8;   // 8 bf16 (4 VGPR)
typedef __attribute__((ext_vector_type(4))) float f32x4;    // MFMA acc

__device__ inline unsigned short f2bf(float f) {            // RNE float->bf16
    union { float f; unsigned u; } v; v.f = f;
    unsigned r = v.u + 0x7FFF + ((v.u >> 16) & 1);
    return (unsigned short)(r >> 16);
}
__device__ inline float bf2f(unsigned short h) {
    union { unsigned u; float f; } v; v.u = ((unsigned)h) << 16;
    return v.f;
}
// split x = hi + lo (both bf16)
__device__ inline void bfsplit(float x, unsigned short& hi, unsigned short& lo) {
    hi = f2bf(x);
    lo = f2bf(x - bf2f(hi));
}
// e_mfma: (br | -bi<<16) -> (bi | br<<16)
__device__ inline bf16x8 derive_im(bf16x8 v) {
    union { bf16x8 v; unsigned u[4]; } in, out;
    in.v = v;
#pragma unroll
    for (int w = 0; w < 4; ++w)
        out.u[w] = ((in.u[w] >> 16) ^ 0x8000u) | (in.u[w] << 16);
    return out.v;
}
// a_mfma: (kx | ky<<16) -> (ky | (-kx)<<16)
__device__ inline bf16x8 derive_im2(bf16x8 v) {
    union { bf16x8 v; unsigned u[4]; } in, out;
    in.v = v;
#pragma unroll
    for (int w = 0; w < 4; ++w)
        out.u[w] = (in.u[w] >> 16) | ((in.u[w] ^ 0x8000u) << 16);
    return out.v;
}

// ---------------------------------------------------------------------------
// Kernel 0 (trig-free): pe[m,i,j] = exp(i*m*theta) = ((dx+i*dy)/r)^m.
// ---------------------------------------------------------------------------
__global__ void pe_kernel(float2* __restrict__ peIJ, float2* __restrict__ peT) {
    int bid = blockIdx.x;           // m*N + i
    int m = bid >> 8;
    int i = bid & 255;
    int j = threadIdx.x;
    float dy = (float)((j >> 4) - (i >> 4));
    float dx = (float)((j & 15) - (i & 15));
    float r2 = dx * dx + dy * dy;
    float c1 = 1.f, s1 = 0.f;
    if (r2 > 0.f) {
        float rinv = rsqrtf(r2);
        c1 = dx * rinv; s1 = dy * rinv;
    }
    float c = 1.f, s = 0.f;
    for (int k = 0; k < m; ++k) {   // m is block-uniform (0..3)
        float nc = c * c1 - s * s1;
        s = c * s1 + s * c1;
        c = nc;
    }
    peIJ[(m * NN + i) * NN + j] = make_float2(c, s);
    peT[(m * NN + j) * NN + i] = make_float2(c, s);
}

// ---------------------------------------------------------------------------
// Kernel 1 (merged convA+convB): blocks 0..95 = convA (emb -> A' split-bf16),
// blocks 96..351 = convB (x -> Bre split-bf16; Bim derived in e_mfma).
// ---------------------------------------------------------------------------
__global__ void convAB_kernel(const float* __restrict__ er, const float* __restrict__ ei,
                              const float* __restrict__ xr, const float* __restrict__ xi,
                              unsigned int* __restrict__ AbfHi, unsigned int* __restrict__ AbfLo,
                              unsigned int* __restrict__ BreHi, unsigned int* __restrict__ BreLo) {
    if (blockIdx.x < 96) {
        int tmh = blockIdx.x;             // 0..95
        int base = tmh * QDD * DD;
#pragma unroll
        for (int it = 0; it < 8; ++it) {
            int idx = threadIdx.x + it * 256;  // q*128+D
            float ar = er[base + idx];
            float ai = ei[base + idx];
            unsigned short arh, arl, aih, ail;
            bfsplit(ar, arh, arl);
            bfsplit(ai, aih, ail);
            AbfHi[base + idx] = (unsigned int)arh | ((unsigned int)aih << 16);
            AbfLo[base + idx] = (unsigned int)arl | ((unsigned int)ail << 16);
        }
        return;
    }
    int bid = blockIdx.x - 96;            // 0..255 = 32 bm x 8 Dg
    int bm = bid >> 3;
    int Dg = bid & 7;
    int D0 = Dg * 16;
    int tid = threadIdx.x;

    __shared__ float sxr[16][257];
    __shared__ float sxi[16][257];

    const float* xrp = xr + (size_t)bm * DD * NN;
    const float* xip = xi + (size_t)bm * DD * NN;
#pragma unroll
    for (int it = 0; it < 16; ++it) {
        int i2 = tid + it * 256;
        int r = i2 >> 8, c = i2 & 255;
        sxr[r][c] = xrp[(size_t)(D0 + r) * NN + c];
        sxi[r][c] = xip[(size_t)(D0 + r) * NN + c];
    }
    __syncthreads();

    int n = tid;
    unsigned int reh[16], rel_[16];
#pragma unroll
    for (int d = 0; d < 16; ++d) {
        float br = sxr[d][n];
        float bi = sxi[d][n];
        unsigned short brh, brl, bih, bil;
        bfsplit(br, brh, brl);
        bfsplit(bi, bih, bil);
        reh[d]  = (unsigned int)brh | ((unsigned int)(bih ^ 0x8000) << 16);
        rel_[d] = (unsigned int)brl | ((unsigned int)(bil ^ 0x8000) << 16);
    }
    size_t ob = (size_t)bm * 32768 + (size_t)n * 128 + D0;
#pragma unroll
    for (int w = 0; w < 4; ++w) {
        ((uint4*)(BreHi + ob))[w] = make_uint4(reh[4*w], reh[4*w+1], reh[4*w+2], reh[4*w+3]);
        ((uint4*)(BreLo + ob))[w] = make_uint4(rel_[4*w], rel_[4*w+1], rel_[4*w+2], rel_[4*w+3]);
    }
}

// ---------------------------------------------------------------------------
// Kernel 2 (e_mfma v5 = v4 + FUSED qe): block = (pair, h, nhalf).
// t=0 plane stays in registers: emits Ea fragments + QE (shfl-reduced);
// E float2 written for t=2 (V) ONLY. t=1 -> Kb fragments.
// ---------------------------------------------------------------------------
__global__ __launch_bounds__(256, 2)
void e_mfma_kernel(const unsigned short* __restrict__ AbfHi,
                   const unsigned short* __restrict__ AbfLo,
                   const unsigned short* __restrict__ BreHi,
                   const unsigned short* __restrict__ BreLo,
                   const float* __restrict__ encr, const float* __restrict__ enci,
                   float2* __restrict__ E,
                   float2* __restrict__ QE,
                   unsigned int* __restrict__ EaHi, unsigned int* __restrict__ EaLo,
                   unsigned int* __restrict__ KbHi, unsigned int* __restrict__ KbLo) {
    int bid = blockIdx.x;                 // 512 = 8 xcd x 64 idx
    int xcd = bid & 7;
    int idx = bid >> 3;                   // 0..63
    int pair = xcd * 4 + (idx & 3);       // b*MM+m (XCD-pinned B panels)
    int h = (idx >> 2) & 7;               // 0..7
    int nhalf = idx >> 5;                 // 0..1
    int b = pair >> 2, m = pair & 3;
    int tid = threadIdx.x;
    int wav = tid >> 6, lane = tid & 63;
    int lo = lane & 15, hi = lane >> 4;

    const unsigned short* AH[3];
    const unsigned short* AL[3];
#pragma unroll
    for (int t = 0; t < 3; ++t) {
        size_t aoff = ((size_t)((t * MM + m) * NHH + h)) * QDD * 256;
        AH[t] = AbfHi + aoff;
        AL[t] = AbfLo + aoff;
    }
    size_t boff = (size_t)pair * 256 * 256;
    const unsigned short* BrH = BreHi + boff;
    const unsigned short* BrL = BreLo + boff;

    f32x4 accRe[3][2], accIm[3][2];
#pragma unroll
    for (int t = 0; t < 3; ++t)
#pragma unroll
        for (int nt = 0; nt < 2; ++nt) {
            accRe[t][nt] = (f32x4)(0.f);
            accIm[t][nt] = (f32x4)(0.f);
        }

#pragma unroll
    for (int ks = 0; ks < 8; ++ks) {
        int k0 = ks * 32;
        int arow = lo * 256 + k0 + hi * 8;
        bf16x8 aH[3], aL[3];
#pragma unroll
        for (int t = 0; t < 3; ++t) {
            aH[t] = *(const bf16x8*)(AH[t] + arow);
            aL[t] = *(const bf16x8*)(AL[t] + arow);
        }
#pragma unroll
        for (int nt = 0; nt < 2; ++nt) {
            int n0 = nhalf * 128 + (wav * 2 + nt) * 16;
            size_t brow = (size_t)(n0 + lo) * 256 + k0 + hi * 8;
            bf16x8 brh = *(const bf16x8*)(BrH + brow);
            bf16x8 brl = *(const bf16x8*)(BrL + brow);
            bf16x8 bih = derive_im(brh);
            bf16x8 bil = derive_im(brl);
#pragma unroll
            for (int t = 0; t < 3; ++t) {
                accRe[t][nt] = __builtin_amdgcn_mfma_f32_16x16x32_bf16(aH[t], brh, accRe[t][nt], 0, 0, 0);
                accRe[t][nt] = __builtin_amdgcn_mfma_f32_16x16x32_bf16(aH[t], brl, accRe[t][nt], 0, 0, 0);
                accRe[t][nt] = __builtin_amdgcn_mfma_f32_16x16x32_bf16(aL[t], brh, accRe[t][nt], 0, 0, 0);
                accIm[t][nt] = __builtin_amdgcn_mfma_f32_16x16x32_bf16(aH[t], bih, accIm[t][nt], 0, 0, 0);
                accIm[t][nt] = __builtin_amdgcn_mfma_f32_16x16x32_bf16(aH[t], bil, accIm[t][nt], 0, 0, 0);
                accIm[t][nt] = __builtin_amdgcn_mfma_f32_16x16x32_bf16(aL[t], bih, accIm[t][nt], 0, 0, 0);
            }
        }
    }

    int bh = b * NHH + h;

    // --- fused qe: QE[b,m,h,i] = sum_q conj(E0[q,i])*enc0[m,h,q] ---
    {
        float cr[4], ci[4];
#pragma unroll
        for (int reg = 0; reg < 4; ++reg) {
            int q = hi * 4 + reg;
            int eb = (m * NHH + h) * QDD + q;
            cr[reg] = encr[eb];
            ci[reg] = enci[eb];
        }
#pragma unroll
        for (int nt = 0; nt < 2; ++nt) {
            int n0 = nhalf * 128 + (wav * 2 + nt) * 16;
            float sr = 0.f, si = 0.f;
#pragma unroll
            for (int reg = 0; reg < 4; ++reg) {
                float erv = accRe[0][nt][reg];
                float eiv = accIm[0][nt][reg];
                // conj(e)*c = (er*cr + ei*ci) + i(er*ci - ei*cr)
                sr = fmaf(erv, cr[reg], fmaf( eiv, ci[reg], sr));
                si = fmaf(erv, ci[reg], fmaf(-eiv, cr[reg], si));
            }
            sr += __shfl_xor(sr, 16); si += __shfl_xor(si, 16);
            sr += __shfl_xor(sr, 32); si += __shfl_xor(si, 32);
            if (hi == 0)
                QE[(size_t)((b * MM + m) * NHH + h) * NN + n0 + lo] = make_float2(sr, si);
        }
    }

    // t=0: Ea fragments ; t=1: Kb fragments ; t=2: E float2 (V).
#pragma unroll
    for (int t = 0; t < 3; ++t) {
        size_t ebase = (size_t)((((t * BB + b) * MM + m) * NHH + h) * QDD) * NN;
#pragma unroll
        for (int nt = 0; nt < 2; ++nt) {
            int n0 = nhalf * 128 + (wav * 2 + nt) * 16;
            if (t == 2) {
#pragma unroll
                for (int reg = 0; reg < 4; ++reg) {
                    int q = hi * 4 + reg;
                    E[ebase + (size_t)q * NN + n0 + lo] =
                        make_float2(accRe[t][nt][reg], accIm[t][nt][reg]);
                }
            }
            if (t < 2) {
                unsigned int hiU[4], loU[4];
#pragma unroll
                for (int reg = 0; reg < 4; ++reg) {
                    unsigned short rh, rl, ih, il;
                    bfsplit(accRe[t][nt][reg], rh, rl);
                    bfsplit(accIm[t][nt][reg], ih, il);
                    hiU[reg] = (unsigned int)rh | ((unsigned int)ih << 16);
                    loU[reg] = (unsigned int)rl | ((unsigned int)il << 16);
                }
                // r = n0/16, ks = m; uint off = (((r*4+ks)*64)+lane)*4
                int r = n0 >> 4;
                size_t fo = (size_t)bh * 16384 + (size_t)((r * 4 + m) * 64 + lane) * 4;
                unsigned int* tH = (t == 0) ? EaHi : KbHi;
                unsigned int* tL = (t == 0) ? EaLo : KbLo;
                *(uint4*)(tH + fo) = make_uint4(hiU[0], hiU[1], hiU[2], hiU[3]);
                *(uint4*)(tL + fo) = make_uint4(loU[0], loU[1], loU[2], loU[3]);
            }
        }
    }
}

// ---------------------------------------------------------------------------
// Kernel 3 (a_mfma v4, coalesced + j-split): 512 blocks.
// ---------------------------------------------------------------------------
__global__ __launch_bounds__(256, 2)
void a_mfma_kernel(const unsigned short* __restrict__ EaHi,
                   const unsigned short* __restrict__ EaLo,
                   const unsigned short* __restrict__ KbHi,
                   const unsigned short* __restrict__ KbLo,
                   const float2* __restrict__ QE,
                   const float2* __restrict__ peIJ,
                   float2* __restrict__ Scores) {
    int bid = blockIdx.x;                 // 512 = 8 xcd x 64 idx
    int xcd = bid & 7;
    int idx = bid >> 3;                   // 0..63
    int bh = xcd * 8 + (idx & 7);         // K-panel XCD-pinned
    int iquad = (idx >> 3) & 3;           // 0..3
    int jhalf = idx >> 5;                 // 0..1
    int b = bh >> 3, h = bh & 7;
    int tid = threadIdx.x;
    int wav = tid >> 6, lane = tid & 63;
    int lo = lane & 15, hi = lane >> 4;
    int it = iquad * 4 + wav;             // this wave's i-tile (0..15)

    const unsigned short* EaH = EaHi + (size_t)bh * 32768;
    const unsigned short* EaL = EaLo + (size_t)bh * 32768;
    const unsigned short* KbH = KbHi + (size_t)bh * 32768;
    const unsigned short* KbL = KbLo + (size_t)bh * 32768;

    f32x4 accRe[8], accIm[8];
#pragma unroll
    for (int nt = 0; nt < 8; ++nt) { accRe[nt] = (f32x4)(0.f); accIm[nt] = (f32x4)(0.f); }

#pragma unroll
    for (int ks = 0; ks < 4; ++ks) {
        size_t arow = (size_t)((it * 4 + ks) * 64 + lane) * 8;   // coalesced
        bf16x8 aH = *(const bf16x8*)(EaH + arow);
        bf16x8 aL = *(const bf16x8*)(EaL + arow);
#pragma unroll
        for (int nt = 0; nt < 8; ++nt) {
            int jt = jhalf * 8 + nt;
            size_t brow = (size_t)((jt * 4 + ks) * 64 + lane) * 8;  // coalesced
            bf16x8 brh = *(const bf16x8*)(KbH + brow);
            bf16x8 brl = *(const bf16x8*)(KbL + brow);
            bf16x8 bih = derive_im2(brh);
            bf16x8 bil = derive_im2(brl);
            accRe[nt] = __builtin_amdgcn_mfma_f32_16x16x32_bf16(aH, brh, accRe[nt], 0, 0, 0);
            accRe[nt] = __builtin_amdgcn_mfma_f32_16x16x32_bf16(aH, brl, accRe[nt], 0, 0, 0);
            accRe[nt] = __builtin_amdgcn_mfma_f32_16x16x32_bf16(aL, brh, accRe[nt], 0, 0, 0);
            accIm[nt] = __builtin_amdgcn_mfma_f32_16x16x32_bf16(aH, bih, accIm[nt], 0, 0, 0);
            accIm[nt] = __builtin_amdgcn_mfma_f32_16x16x32_bf16(aH, bil, accIm[nt], 0, 0, 0);
            accIm[nt] = __builtin_amdgcn_mfma_f32_16x16x32_bf16(aL, bih, accIm[nt], 0, 0, 0);
        }
    }

    // epilogue: + sum_m QE[b,m,h,i]*pe[m,i,j]; write Scores.
    float2 qe[MM][4];
#pragma unroll
    for (int m = 0; m < MM; ++m)
#pragma unroll
        for (int reg = 0; reg < 4; ++reg) {
            int i = it * 16 + hi * 4 + reg;
            qe[m][reg] = QE[(size_t)((b * MM + m) * NHH + h) * NN + i];
        }

#pragma unroll
    for (int nt = 0; nt < 8; ++nt) {
#pragma unroll
        for (int reg = 0; reg < 4; ++reg) {
            int i = it * 16 + hi * 4 + reg;
            int j = (jhalf * 8 + nt) * 16 + lo;
            float ar = accRe[nt][reg];
            float ai = accIm[nt][reg];
#pragma unroll
            for (int m = 0; m < MM; ++m) {
                float2 p = peIJ[(size_t)(m * NN + i) * NN + j];
                float2 e1 = qe[m][reg];
                ar = fmaf(e1.x, p.x, fmaf(-e1.y, p.y, ar));
                ai = fmaf(e1.x, p.y, fmaf( e1.y, p.x, ai));
            }
            Scores[(size_t)(bh * NN + i) * NN + j] = make_float2(ar, ai);
        }
    }
}

// ---------------------------------------------------------------------------
// Kernel 4: row softmax of |A|/4 over j; writes TRANSPOSED Aw:
//   AwT[(bh*N + j)*N + i]
// ---------------------------------------------------------------------------
__global__ void softmax_kernel(const float2* __restrict__ A, float* __restrict__ AwT) {
    int row = blockIdx.x;                 // (b*NHH+h)*NN + i
    int j = threadIdx.x;
    float2 a = A[(size_t)row * NN + j];
    float v = sqrtf(fmaf(a.x, a.x, a.y * a.y)) * 0.25f;

    __shared__ float smax[4];
    __shared__ float ssum[4];
    int lane = threadIdx.x & 63;
    int wid  = threadIdx.x >> 6;

    float mv = v;
#pragma unroll
    for (int off = 32; off > 0; off >>= 1) mv = fmaxf(mv, __shfl_xor(mv, off));
    if (lane == 0) smax[wid] = mv;
    __syncthreads();
    float mx = fmaxf(fmaxf(smax[0], smax[1]), fmaxf(smax[2], smax[3]));

    float e = expf(v - mx);
    float sv = e;
#pragma unroll
    for (int off = 32; off > 0; off >>= 1) sv += __shfl_xor(sv, off);
    if (lane == 0) ssum[wid] = sv;
    __syncthreads();
    float sum = ssum[0] + ssum[1] + ssum[2] + ssum[3];

    float aw = e / sum;
    int bh = row >> 8;
    int i  = row & 255;
    AwT[(size_t)(bh * NN + j) * NN + i] = aw;
}

// ---------------------------------------------------------------------------
// Kernel 5 (qh-split + XCD swizzle): 512 blocks = 64 idx x 8 xcd.
// ---------------------------------------------------------------------------
__global__ __launch_bounds__(512)
void res_kernel(const float2* __restrict__ E, const float* __restrict__ AwT,
                const float2* __restrict__ peT,
                const float* __restrict__ encr, const float* __restrict__ enci,
                float2* __restrict__ Res) {
    int bid = blockIdx.x;
    int xcd = bid & 7;
    int idx = bid >> 3;                   // 0..63
    int bh = xcd * 8 + (idx & 7);         // b*NHH+h
    int mqh = idx >> 3;                   // 0..7
    int m  = mqh >> 1;
    int qh = mqh & 1;
    int h = bh & 7;
    int b = bh >> 3;
    int i = threadIdx.x & 255;
    int g = threadIdx.x >> 8;             // j-half 0/1

    __shared__ float2 sv[8][NN];          // 16 KB: this qh's 8 V rows
    __shared__ float2 spA[NN][9];         // 18 KB: g=1 partials (8 acc + PA)
    __shared__ float2 senc[8];

    const float2* V = E + ((size_t)(((2 * BB + b) * MM + m) * NHH + h) * QDD + qh * 8) * NN;
    for (int i2 = threadIdx.x; i2 < 8 * NN; i2 += 512) sv[i2 >> 8][i2 & 255] = V[i2];
    if (threadIdx.x < 8) {
        int eb = ((MM + m) * NHH + h) * QDD + qh * 8 + threadIdx.x;   // enc[1,...]
        senc[threadIdx.x] = make_float2(encr[eb], enci[eb]);
    }
    __syncthreads();

    float accr[8], acci[8];
#pragma unroll
    for (int q = 0; q < 8; ++q) { accr[q] = 0.f; acci[q] = 0.f; }
    float par = 0.f, pai = 0.f;

    const float*  awp = AwT + (size_t)((b * NHH + h) * NN) * NN + i;
    const float2* pep = peT + (size_t)(m * NN) * NN + i;
    int j0 = g * (NN / 2);
    for (int j = j0; j < j0 + NN / 2; ++j) {
        float aw  = awp[(size_t)j * NN];      // coalesced over i
        float2 p  = pep[(size_t)j * NN];      // coalesced over i
        par = fmaf(p.x, aw, par);
        pai = fmaf(p.y, aw, pai);
#pragma unroll
        for (int q = 0; q < 8; ++q) {
            float2 vv = sv[q][j];             // wave-uniform -> broadcast
            accr[q] = fmaf(vv.x, aw, accr[q]);
            acci[q] = fmaf(vv.y, aw, acci[q]);
        }
    }

    if (g == 1) {
#pragma unroll
        for (int q = 0; q < 8; ++q) spA[i][q] = make_float2(accr[q], acci[q]);
        spA[i][8] = make_float2(par, pai);
    }
    __syncthreads();
    if (g == 0) {
#pragma unroll
        for (int q = 0; q < 8; ++q) {
            float2 o = spA[i][q];
            accr[q] += o.x; acci[q] += o.y;
        }
        float2 o = spA[i][8];
        par += o.x; pai += o.y;

        float2* rp = Res + ((size_t)((b * MM + m) * KO + h * QDD + qh * 8)) * NN + i;
#pragma unroll
        for (int q = 0; q < 8; ++q) {
            float2 e1 = senc[q];
            float rr = accr[q] + e1.x * par - e1.y * pai;
            float ri = acci[q] + e1.x * pai + e1.y * par;
            rp[(size_t)q * NN] = make_float2(rr, ri);
        }
    }
}

// ---------------------------------------------------------------------------
// Kernel 6 (DTILE=8 + XCD swizzle): out[b,m,D,n] = sum_k w_out*res.
// ---------------------------------------------------------------------------
__global__ void out_kernel(const float2* __restrict__ Res,
                           const float* __restrict__ wor, const float* __restrict__ woi,
                           float* __restrict__ out) {
    int bid = blockIdx.x;
    int xcd = bid & 7;
    int idx = bid >> 3;                   // 0..63
    int bm = xcd * 4 + (idx & 3);         // b*MM+m, 0..31
    int dt = idx >> 2;                    // 0..15
    int n = threadIdx.x;
    int D0 = dt * DTILE;
    int m = bm & 3;

    __shared__ float2 sw[DTILE][KO];      // 8 KB
    for (int i2 = threadIdx.x; i2 < DTILE * KO; i2 += 256) {
        int d = i2 >> 7, k = i2 & 127;
        int wb = (m * DD + D0 + d) * KO + k;
        sw[d][k] = make_float2(wor[wb], woi[wb]);
    }
    __syncthreads();

    const float2* rp = Res + (size_t)(bm * KO) * NN + n;
    float ar[DTILE], ai[DTILE];
#pragma unroll
    for (int d = 0; d < DTILE; ++d) { ar[d] = 0.f; ai[d] = 0.f; }

    for (int k = 0; k < KO; ++k) {
        float2 r = rp[(size_t)k * NN];    // coalesced
#pragma unroll
        for (int d = 0; d < DTILE; ++d) {
            float2 w = sw[d][k];          // broadcast
            ar[d] = fmaf(w.x, r.x, fmaf(-w.y, r.y, ar[d]));
            ai[d] = fmaf(w.x, r.y, fmaf( w.y, r.x, ai[d]));
        }
    }
#pragma unroll
    for (int d = 0; d < DTILE; ++d) {
        size_t ob = (size_t)(bm * DD + D0 + d) * NN + n;
        out[ob] = ar[d];
        out[(size_t)BB * MM * DD * NN + ob] = ai[d];
    }
}

// ---------------------------------------------------------------------------
extern "C" void kernel_launch(void* const* d_in, const int* in_sizes, int n_in,
                              void* d_out, int out_size, void* d_ws, size_t ws_size,
                              hipStream_t stream) {
    (void)in_sizes; (void)n_in; (void)out_size; (void)ws_size;

    const float* x_re   = (const float*)d_in[0];
    const float* x_im   = (const float*)d_in[1];
    const float* emb_re = (const float*)d_in[2];
    const float* emb_im = (const float*)d_in[3];
    const float* enc_re = (const float*)d_in[4];
    const float* enc_im = (const float*)d_in[5];
    const float* out_re = (const float*)d_in[6];
    const float* out_im = (const float*)d_in[7];
    float* out = (float*)d_out;

    // Workspace layout (floats). Total ~155.7 MB.
    float* ws = (float*)d_ws;
    size_t off = 0;
    float2* peIJ = (float2*)(ws + off); off += (size_t)MM * NN * NN * 2;          // 524288
    float2* peT  = (float2*)(ws + off); off += (size_t)MM * NN * NN * 2;          // 524288
    float2* E    = (float2*)(ws + off); off += (size_t)3 * BB * MM * NHH * QDD * NN * 2; // 25165824
    float2* QE   = (float2*)(ws + off); off += (size_t)BB * MM * NHH * NN * 2;    // 131072
    float2* A    = (float2*)(ws + off); off += (size_t)BB * NHH * NN * NN * 2;    // 8388608 fl
    float*  AwT  = (float*)(ws + off);  off += (size_t)BB * NHH * NN * NN;        // 4194304 fl

    // Region plan (same as r33, verified):
    //  1) convAB stages Abf/Bre in A region; e_mfma reads them ->
    //     writes E t2 (V) float2 + QE + Ea/Kb fragments into AwT region.
    //  2) a_mfma reads Ea/Kb(AwT region) -> Scores over FULL A region.
    //  3) softmax reads Scores(A) -> writes AwT (Ea/Kb dead).
    //  4) res reads AwT + V(E t2) -> Res into A region start (Scores dead).
    unsigned int* AbfHi = (unsigned int*)A;
    unsigned int* AbfLo = AbfHi + (size_t)96 * QDD * DD;
    unsigned int* BreHi = AbfLo + (size_t)96 * QDD * DD;
    unsigned int* BreLo = BreHi + (size_t)32 * 256 * 128;

    unsigned int* EaHi = (unsigned int*)AwT;                      // 4 x 1048576 uints
    unsigned int* EaLo = EaHi + (size_t)64 * 16384;               //  = 16.78MB exact
    unsigned int* KbHi = EaLo + (size_t)64 * 16384;
    unsigned int* KbLo = KbHi + (size_t)64 * 16384;

    float2* Scores = A;   // full 33.5MB A region
    float2* Res    = A;   // first 8.4MB of A region, after Scores is dead

    pe_kernel<<<MM * NN, 256, 0, stream>>>(peIJ, peT);
    convAB_kernel<<<96 + 256, 256, 0, stream>>>(emb_re, emb_im, x_re, x_im,
                                                AbfHi, AbfLo, BreHi, BreLo);
    e_mfma_kernel<<<512, 256, 0, stream>>>(
        (const unsigned short*)AbfHi, (const unsigned short*)AbfLo,
        (const unsigned short*)BreHi, (const unsigned short*)BreLo,
        enc_re, enc_im, E, QE,
        EaHi, EaLo, KbHi, KbLo);
    a_mfma_kernel<<<512, 256, 0, stream>>>(
        (const unsigned short*)EaHi, (const unsigned short*)EaLo,
        (const unsigned short*)KbHi, (const unsigned short*)KbLo,
        QE, peIJ, Scores);
    softmax_kernel<<<BB * NHH * NN, 256, 0, stream>>>(Scores, AwT);
    res_kernel<<<BB * MM * NHH * 2, 512, 0, stream>>>(E, AwT, peT, enc_re, enc_im, Res);
    out_kernel<<<BB * MM * (DD / DTILE), 256, 0, stream>>>(Res, out_re, out_im, out);
}